// Round 12
// baseline (454.663 us; speedup 1.0000x reference)
//
#include <hip/hip_runtime.h>
#include <hip/hip_bf16.h>
#include <hip/hip_fp16.h>

#define IN_CH 64
#define HID 32
#define HEADS 4
#define OUT_CH 6
#define NEG_SLOPE 0.2f

typedef __attribute__((ext_vector_type(8))) _Float16 half8;
typedef __attribute__((ext_vector_type(4))) float f32x4;

// ============== CSR build: bucket-partitioned, LDS-atomic only ==============

#define PBLK 256
#define CAP 6144

__global__ __launch_bounds__(256) void part_count(const int* __restrict__ ei, int E, int EN,
                                                  int NB, int epb, int* __restrict__ counts) {
    __shared__ int cnt[512];
    int b = blockIdx.x, t = threadIdx.x;
    for (int i = t; i < NB; i += 256) cnt[i] = 0;
    __syncthreads();
    int e0 = b * epb;
    int e1 = min(e0 + epb, EN);
    for (int e = e0 + t; e < e1; e += 256) {
        int d = (e < E) ? ei[E + e] : (e - E);
        atomicAdd(&cnt[d >> 8], 1);
    }
    __syncthreads();
    for (int i = t; i < NB; i += 256) counts[(size_t)i * PBLK + b] = cnt[i];
}

__global__ __launch_bounds__(256) void bucket_tot(const int* __restrict__ counts,
                                                  int* __restrict__ btot) {
    __shared__ int red[256];
    int k = blockIdx.x, t = threadIdx.x;
    red[t] = counts[(size_t)k * PBLK + t];
    __syncthreads();
    for (int off = 128; off; off >>= 1) {
        if (t < off) red[t] += red[t + off];
        __syncthreads();
    }
    if (t == 0) btot[k] = red[0];
}

__global__ __launch_bounds__(256) void bucket_scan(const int* __restrict__ btot, int NB, int EN,
                                                   int* __restrict__ bstart) {
    __shared__ int tmp[256];
    int t = threadIdx.x;
    int chunk = (NB + 255) >> 8;
    int s0 = t * chunk, s1 = min(s0 + chunk, NB);
    int sum = 0;
    for (int i = s0; i < s1; ++i) sum += btot[i];
    tmp[t] = sum;
    __syncthreads();
    for (int off = 1; off < 256; off <<= 1) {
        int v = (t >= off) ? tmp[t - off] : 0;
        __syncthreads();
        tmp[t] += v;
        __syncthreads();
    }
    int run = (t == 0) ? 0 : tmp[t - 1];
    for (int i = s0; i < s1; ++i) {
        int c = btot[i];
        bstart[i] = run;
        run += c;
    }
    if (t == 255) bstart[NB] = EN;
}

__global__ __launch_bounds__(256) void bucket_base(int* __restrict__ counts,
                                                   const int* __restrict__ bstart) {
    __shared__ int sc[256];
    int k = blockIdx.x, t = threadIdx.x;
    int v = counts[(size_t)k * PBLK + t];
    sc[t] = v;
    __syncthreads();
    for (int off = 1; off < 256; off <<= 1) {
        int u = (t >= off) ? sc[t - off] : 0;
        __syncthreads();
        sc[t] += u;
        __syncthreads();
    }
    counts[(size_t)k * PBLK + t] = bstart[k] + sc[t] - v;
}

__global__ __launch_bounds__(256) void part_scatter(const int* __restrict__ ei, int E, int EN,
                                                    int NB, int epb,
                                                    const int* __restrict__ base,
                                                    int2* __restrict__ ebuf) {
    __shared__ int cur[512];
    int b = blockIdx.x, t = threadIdx.x;
    for (int i = t; i < NB; i += 256) cur[i] = base[(size_t)i * PBLK + b];
    __syncthreads();
    int e0 = b * epb;
    int e1 = min(e0 + epb, EN);
    for (int e = e0 + t; e < e1; e += 256) {
        int s, d;
        if (e < E) { s = ei[e]; d = ei[E + e]; }
        else       { s = e - E; d = s; }
        int slot = atomicAdd(&cur[d >> 8], 1);
        ebuf[slot] = make_int2(s, d & 255);
    }
}

__global__ __launch_bounds__(256) void bucket_csr(const int2* __restrict__ ebuf,
                                                  const int* __restrict__ bstart,
                                                  int NB, int N, int EN,
                                                  int* __restrict__ row_start,
                                                  int* __restrict__ csr_src) {
    __shared__ int cnt[256];
    __shared__ int sc[256];
    __shared__ int stage[CAP];
    int k = blockIdx.x, t = threadIdx.x;
    int s0 = bstart[k], s1 = bstart[k + 1];
    int len = s1 - s0;
    cnt[t] = 0;
    __syncthreads();
    for (int i = t; i < len; i += 256) atomicAdd(&cnt[ebuf[s0 + i].y], 1);
    __syncthreads();
    int v = cnt[t];
    sc[t] = v;
    __syncthreads();
    for (int off = 1; off < 256; off <<= 1) {
        int u = (t >= off) ? sc[t - off] : 0;
        __syncthreads();
        sc[t] += u;
        __syncthreads();
    }
    int excl = sc[t] - v;
    int g = (k << 8) + t;
    if (g < N) row_start[g] = s0 + excl;
    if (k == NB - 1 && t == 0) row_start[N] = EN;
    bool fits = (len <= CAP);
    cnt[t] = fits ? excl : s0 + excl;
    __syncthreads();
    if (fits) {
        for (int i = t; i < len; i += 256) {
            int2 e = ebuf[s0 + i];
            int slot = atomicAdd(&cnt[e.y], 1);
            stage[slot] = e.x;
        }
        __syncthreads();
        for (int i = t; i < len; i += 256) csr_src[s0 + i] = stage[i];
    } else {
        for (int i = t; i < len; i += 256) {
            int2 e = ebuf[s0 + i];
            int slot = atomicAdd(&cnt[e.y], 1);
            csr_src[slot] = e.x;
        }
    }
}

// ---------------- weight transpose ----------------

__global__ void wtrans_kernel(const float* __restrict__ W, __half* __restrict__ WT,
                              int K, int kshift) {
    int o = blockIdx.x * blockDim.x + threadIdx.x;
    if (o >= (K << 7)) return;
    int c = o >> kshift;
    int k = o & (K - 1);
    WT[o] = __float2half(W[(size_t)k * 128 + c]);
}

// ------- MFMA GEMM: C[N][128](fp16) = A[N][K] @ W, + als/ald -------
// Per wave: 16 rows x 128 cols. K==64: A read fp32 from Af and converted
// in-register (layer 0). C layout: col=lane&15, row=(lane>>4)*4+reg.

__global__ __launch_bounds__(256) void gemm_mfma(const __half* __restrict__ A,
                                                 const float* __restrict__ Af,
                                                 const __half* __restrict__ WT,
                                                 const float* __restrict__ avs,
                                                 const float* __restrict__ avd,
                                                 __half* __restrict__ C,
                                                 float* __restrict__ als,
                                                 float* __restrict__ ald,
                                                 int N, int K) {
    int tid = threadIdx.x;
    int wv = tid >> 6, lane = tid & 63;
    int row0 = blockIdx.x * 64 + wv * 16;
    int lrow = lane & 15;
    int lk = (lane >> 4) * 8;
    int garow = row0 + lrow;

    half8 afrag[4];
#pragma unroll
    for (int ks = 0; ks < 4; ++ks) {
        half8 z = {(_Float16)0, (_Float16)0, (_Float16)0, (_Float16)0,
                   (_Float16)0, (_Float16)0, (_Float16)0, (_Float16)0};
        afrag[ks] = z;
    }
    if (garow < N) {
        if (K == 128) {
            const __half* ap = A + (size_t)garow * 128 + lk;
#pragma unroll
            for (int ks = 0; ks < 4; ++ks)
                afrag[ks] = *reinterpret_cast<const half8*>(ap + ks * 32);
        } else {
            const float* ap = Af + (size_t)garow * 64 + lk;
#pragma unroll
            for (int ks = 0; ks < 2; ++ks) {
                float4 f0 = *reinterpret_cast<const float4*>(ap + ks * 32);
                float4 f1 = *reinterpret_cast<const float4*>(ap + ks * 32 + 4);
                half8 fr = {(_Float16)f0.x, (_Float16)f0.y, (_Float16)f0.z, (_Float16)f0.w,
                            (_Float16)f1.x, (_Float16)f1.y, (_Float16)f1.z, (_Float16)f1.w};
                afrag[ks] = fr;
            }
        }
    }

    f32x4 acc[8];
#pragma unroll
    for (int t = 0; t < 8; ++t) acc[t] = (f32x4){0.f, 0.f, 0.f, 0.f};

#pragma unroll
    for (int t = 0; t < 8; ++t) {
        const __half* wb = WT + (size_t)(t * 16 + lrow) * K + lk;
        if (K == 128) {
#pragma unroll
            for (int ks = 0; ks < 4; ++ks) {
                half8 bfrag = *reinterpret_cast<const half8*>(wb + ks * 32);
                acc[t] = __builtin_amdgcn_mfma_f32_16x16x32_f16(afrag[ks], bfrag, acc[t], 0, 0, 0);
            }
        } else {
#pragma unroll
            for (int ks = 0; ks < 2; ++ks) {
                half8 bfrag = *reinterpret_cast<const half8*>(wb + ks * 32);
                acc[t] = __builtin_amdgcn_mfma_f32_16x16x32_f16(afrag[ks], bfrag, acc[t], 0, 0, 0);
            }
        }
    }

    int rbase = (lane >> 4) * 4;
#pragma unroll
    for (int t = 0; t < 8; ++t) {
#pragma unroll
        for (int j = 0; j < 4; ++j) {
            int gr = row0 + rbase + j;
            if (gr < N) C[(size_t)gr * 128 + t * 16 + lrow] = __float2half(acc[t][j]);
        }
    }
    float ps[4][4], pd[4][4];
#pragma unroll
    for (int h = 0; h < 4; ++h)
#pragma unroll
        for (int j = 0; j < 4; ++j) { ps[h][j] = 0.f; pd[h][j] = 0.f; }
#pragma unroll
    for (int t = 0; t < 8; ++t) {
        int ht = t >> 1;
        float as_c = avs[t * 16 + lrow];
        float ad_c = avd[t * 16 + lrow];
#pragma unroll
        for (int j = 0; j < 4; ++j) {
            ps[ht][j] += acc[t][j] * as_c;
            pd[ht][j] += acc[t][j] * ad_c;
        }
    }
#pragma unroll
    for (int h = 0; h < 4; ++h) {
#pragma unroll
        for (int j = 0; j < 4; ++j) {
            float s = ps[h][j], d = pd[h][j];
            s += __shfl_xor(s, 1); d += __shfl_xor(d, 1);
            s += __shfl_xor(s, 2); d += __shfl_xor(d, 2);
            s += __shfl_xor(s, 4); d += __shfl_xor(d, 4);
            s += __shfl_xor(s, 8); d += __shfl_xor(d, 8);
            if (lrow == 0) {
                int gr = row0 + rbase + j;
                if (gr < N) {
                    als[(size_t)gr * 4 + h] = s;
                    ald[(size_t)gr * 4 + h] = d;
                }
            }
        }
    }
}

// ------- wave-per-node aggregation, fp16 h, LDS exp-sharing (v3) -------
// Phase 1: each lane computes its OWN edge's 4 exps once (als L2-resident),
// stores {ex4, s} to per-wave LDS. Phase 2: deep-unrolled h-gather reads
// ex/s via broadcast LDS reads, pure fma-mix accumulation. Intra-wave LDS
// is in-order -> no __syncthreads (divergent trip counts across waves).

__device__ __forceinline__ float lrelu(float x) { return x > 0.f ? x : NEG_SLOPE * x; }

__global__ __launch_bounds__(256) void agg_kernel(const __half* __restrict__ h,
                                                  const float* __restrict__ als4,
                                                  const float* __restrict__ ald4,
                                                  const int* __restrict__ row_start,
                                                  const int* __restrict__ csr_src,
                                                  const float* __restrict__ bias,
                                                  __half* __restrict__ xout,
                                                  int N, int applyElu) {
    __shared__ float ex_s[4][256];
    __shared__ int   so_s[4][64];
    int w = threadIdx.x >> 6;
    int v = blockIdx.x * 4 + w;
    int lane = threadIdx.x & 63;
    if (v >= N) return;
    int base = row_start[v], end = row_start[v + 1];

    int half_ = lane >> 5;
    int dim4 = (lane & 31) * 4;
    int hd2  = (lane & 31) >> 3;

    float4 aldv = *reinterpret_cast<const float4*>(ald4 + (size_t)v * 4);
    float4 alsv = *reinterpret_cast<const float4*>(als4 + (size_t)v * 4);
    float4 em4;
    em4.x = lrelu(alsv.x + aldv.x);
    em4.y = lrelu(alsv.y + aldv.y);
    em4.z = lrelu(alsv.z + aldv.z);
    em4.w = lrelu(alsv.w + aldv.w);

    const __half* hdim = h + dim4;
    float4 sum4 = make_float4(0.f, 0.f, 0.f, 0.f);
    float4 acc  = make_float4(0.f, 0.f, 0.f, 0.f);
    float4 acc2 = make_float4(0.f, 0.f, 0.f, 0.f);

    for (int c = base; c < end; c += 64) {
        int j = c + lane;
        bool valid = j < end;
        int s = valid ? csr_src[j] : 0;
        float4 ex4 = make_float4(0.f, 0.f, 0.f, 0.f);
        if (valid) {
            float4 a = *reinterpret_cast<const float4*>(als4 + (size_t)s * 4);
            ex4.x = __expf(lrelu(a.x + aldv.x) - em4.x);
            ex4.y = __expf(lrelu(a.y + aldv.y) - em4.y);
            ex4.z = __expf(lrelu(a.z + aldv.z) - em4.z);
            ex4.w = __expf(lrelu(a.w + aldv.w) - em4.w);
            sum4.x += ex4.x; sum4.y += ex4.y; sum4.z += ex4.z; sum4.w += ex4.w;
        }
        *reinterpret_cast<float4*>(&ex_s[w][lane * 4]) = ex4;
        so_s[w][lane] = s;
        __builtin_amdgcn_wave_barrier();
        asm volatile("" ::: "memory");

        int cnt = end - c; if (cnt > 64) cnt = 64;
        int t = half_;
        for (; t + 6 < cnt; t += 8) {
            int i0 = t, i1 = t + 2, i2 = t + 4, i3 = t + 6;
            int s0 = so_s[w][i0], s1 = so_s[w][i1], s2 = so_s[w][i2], s3 = so_s[w][i3];
            float e0 = ex_s[w][i0 * 4 + hd2], e1 = ex_s[w][i1 * 4 + hd2];
            float e2 = ex_s[w][i2 * 4 + hd2], e3 = ex_s[w][i3 * 4 + hd2];
            union { uint2 u; __half hh[4]; } r0, r1, r2, r3;
            r0.u = *reinterpret_cast<const uint2*>(hdim + (size_t)s0 * 128);
            r1.u = *reinterpret_cast<const uint2*>(hdim + (size_t)s1 * 128);
            r2.u = *reinterpret_cast<const uint2*>(hdim + (size_t)s2 * 128);
            r3.u = *reinterpret_cast<const uint2*>(hdim + (size_t)s3 * 128);
            acc.x  += e0 * (float)r0.hh[0]; acc.y  += e0 * (float)r0.hh[1];
            acc.z  += e0 * (float)r0.hh[2]; acc.w  += e0 * (float)r0.hh[3];
            acc2.x += e1 * (float)r1.hh[0]; acc2.y += e1 * (float)r1.hh[1];
            acc2.z += e1 * (float)r1.hh[2]; acc2.w += e1 * (float)r1.hh[3];
            acc.x  += e2 * (float)r2.hh[0]; acc.y  += e2 * (float)r2.hh[1];
            acc.z  += e2 * (float)r2.hh[2]; acc.w  += e2 * (float)r2.hh[3];
            acc2.x += e3 * (float)r3.hh[0]; acc2.y += e3 * (float)r3.hh[1];
            acc2.z += e3 * (float)r3.hh[2]; acc2.w += e3 * (float)r3.hh[3];
        }
        for (; t < cnt; t += 2) {
            int s0 = so_s[w][t];
            float e0 = ex_s[w][t * 4 + hd2];
            union { uint2 u; __half hh[4]; } r0;
            r0.u = *reinterpret_cast<const uint2*>(hdim + (size_t)s0 * 128);
            acc.x += e0 * (float)r0.hh[0]; acc.y += e0 * (float)r0.hh[1];
            acc.z += e0 * (float)r0.hh[2]; acc.w += e0 * (float)r0.hh[3];
        }
        __builtin_amdgcn_wave_barrier();
        asm volatile("" ::: "memory");
    }
    acc.x += acc2.x; acc.y += acc2.y; acc.z += acc2.z; acc.w += acc2.w;
    acc.x += __shfl_xor(acc.x, 32);
    acc.y += __shfl_xor(acc.y, 32);
    acc.z += __shfl_xor(acc.z, 32);
    acc.w += __shfl_xor(acc.w, 32);
#pragma unroll
    for (int off = 32; off; off >>= 1) {
        sum4.x += __shfl_xor(sum4.x, off);
        sum4.y += __shfl_xor(sum4.y, off);
        sum4.z += __shfl_xor(sum4.z, off);
        sum4.w += __shfl_xor(sum4.w, off);
    }
    if (lane < 32) {
        float ssum = (hd2 == 0) ? sum4.x : (hd2 == 1) ? sum4.y : (hd2 == 2) ? sum4.z : sum4.w;
        float inv = 1.0f / (ssum + 1e-16f);
        float4 bv = *reinterpret_cast<const float4*>(bias + dim4);
        float4 o;
        o.x = acc.x * inv + bv.x;
        o.y = acc.y * inv + bv.y;
        o.z = acc.z * inv + bv.z;
        o.w = acc.w * inv + bv.w;
        if (applyElu) {
            o.x = o.x > 0.f ? o.x : expm1f(o.x);
            o.y = o.y > 0.f ? o.y : expm1f(o.y);
            o.z = o.z > 0.f ? o.z : expm1f(o.z);
            o.w = o.w > 0.f ? o.w : expm1f(o.w);
        }
        __half2* op = reinterpret_cast<__half2*>(xout + (size_t)v * 128 + dim4);
        op[0] = __float22half2_rn(make_float2(o.x, o.y));
        op[1] = __float22half2_rn(make_float2(o.z, o.w));
    }
}

// ---------------- layer 3: GEMM [N,128]x[128,6] with fused al ----------------

__global__ void gemm3_kernel(const __half* __restrict__ x, const float* __restrict__ W,
                             const float* __restrict__ as3, const float* __restrict__ ad3,
                             float* __restrict__ h3, float* __restrict__ als3,
                             float* __restrict__ ald3, int N) {
    int n = blockIdx.x * blockDim.x + threadIdx.x;
    if (n >= N) return;
    float acc[6] = {0.f, 0.f, 0.f, 0.f, 0.f, 0.f};
    const __half* xp = x + (size_t)n * 128;
#pragma unroll 2
    for (int k8 = 0; k8 < 16; ++k8) {
        union { uint4 u; __half hh[8]; } rv;
        rv.u = *reinterpret_cast<const uint4*>(xp + k8 * 8);
        const float* w0 = W + (size_t)(k8 * 8) * 6;
#pragma unroll
        for (int kk = 0; kk < 8; ++kk) {
            float xv = (float)rv.hh[kk];
#pragma unroll
            for (int q = 0; q < 6; ++q)
                acc[q] += xv * w0[kk * 6 + q];
        }
    }
    float s = 0.f, d = 0.f;
#pragma unroll
    for (int q = 0; q < 6; ++q) {
        s += acc[q] * as3[q];
        d += acc[q] * ad3[q];
        h3[(size_t)n * 6 + q] = acc[q];
    }
    als3[n] = s;
    ald3[n] = d;
}

__global__ void agg3_kernel(const float* __restrict__ h3, const float* __restrict__ als3,
                            const float* __restrict__ ald3, const int* __restrict__ row_start,
                            const int* __restrict__ csr_src, const float* __restrict__ b3,
                            float* __restrict__ out, int N) {
    int v = blockIdx.x * blockDim.x + threadIdx.x;
    if (v >= N) return;
    int base = row_start[v], end = row_start[v + 1];
    float aldv = ald3[v];
    float em = lrelu(als3[v] + aldv);
    float ssum = 0.f;
    float acc[6] = {0.f, 0.f, 0.f, 0.f, 0.f, 0.f};
    float acc2[6] = {0.f, 0.f, 0.f, 0.f, 0.f, 0.f};
    int j = base;
    for (; j + 1 < end; j += 2) {
        int sa = csr_src[j], sb = csr_src[j + 1];
        float ea = __expf(lrelu(als3[sa] + aldv) - em);
        float eb = __expf(lrelu(als3[sb] + aldv) - em);
        ssum += ea + eb;
        const float* ha = h3 + (size_t)sa * 6;
        const float* hb = h3 + (size_t)sb * 6;
#pragma unroll
        for (int q = 0; q < 6; ++q) acc[q] += ea * ha[q];
#pragma unroll
        for (int q = 0; q < 6; ++q) acc2[q] += eb * hb[q];
    }
    if (j < end) {
        int sa = csr_src[j];
        float ea = __expf(lrelu(als3[sa] + aldv) - em);
        ssum += ea;
        const float* ha = h3 + (size_t)sa * 6;
#pragma unroll
        for (int q = 0; q < 6; ++q) acc[q] += ea * ha[q];
    }
    float inv = 1.f / (ssum + 1e-16f);
#pragma unroll
    for (int q = 0; q < 6; ++q) out[(size_t)v * 6 + q] = (acc[q] + acc2[q]) * inv + b3[q];
}

// ---------------- launch ----------------

extern "C" void kernel_launch(void* const* d_in, const int* in_sizes, int n_in,
                              void* d_out, int out_size, void* d_ws, size_t ws_size,
                              hipStream_t stream) {
    const float* x    = (const float*)d_in[0];
    const int*   ei   = (const int*)d_in[1];
    const float* W0   = (const float*)d_in[3];
    const float* as0  = (const float*)d_in[4];
    const float* ad0  = (const float*)d_in[5];
    const float* b0   = (const float*)d_in[6];
    const float* W1   = (const float*)d_in[7];
    const float* as1  = (const float*)d_in[8];
    const float* ad1  = (const float*)d_in[9];
    const float* b1   = (const float*)d_in[10];
    const float* W2   = (const float*)d_in[11];
    const float* as2  = (const float*)d_in[12];
    const float* ad2  = (const float*)d_in[13];
    const float* b2   = (const float*)d_in[14];
    const float* W3   = (const float*)d_in[15];
    const float* as3  = (const float*)d_in[16];
    const float* ad3  = (const float*)d_in[17];
    const float* b3   = (const float*)d_in[18];
    float* out = (float*)d_out;

    int N = in_sizes[0] / IN_CH;
    int E = in_sizes[1] / 2;
    int EN = E + N;
    int NB = (N + 255) >> 8;
    int epb = (EN + PBLK - 1) / PBLK;

    char* p = (char*)d_ws;
    auto alloc = [&](size_t bytes) {
        char* q = p;
        p += (bytes + 255) & ~(size_t)255;
        return q;
    };
    __half* hbuf = (__half*)alloc((size_t)N * 128 * 2);
    __half* xA   = (__half*)alloc((size_t)N * 128 * 2);
    __half* xB   = (__half*)alloc((size_t)N * 128 * 2);
    __half* WT0  = (__half*)alloc((size_t)128 * 64 * 2);
    __half* WT1  = (__half*)alloc((size_t)128 * 128 * 2);
    __half* WT2  = (__half*)alloc((size_t)128 * 128 * 2);
    float* als  = (float*)alloc((size_t)N * 4 * 4);
    float* ald  = (float*)alloc((size_t)N * 4 * 4);
    float* h3   = (float*)alloc((size_t)N * 6 * 4);
    float* als3 = (float*)alloc((size_t)N * 4);
    float* ald3 = (float*)alloc((size_t)N * 4);
    int* row_start = (int*)alloc((size_t)(N + 1) * 4);
    int* csr_src   = (int*)alloc((size_t)EN * 4);
    int2* ebuf     = (int2*)alloc((size_t)EN * 8);
    int* counts    = (int*)alloc((size_t)NB * PBLK * 4);
    int* btot      = (int*)alloc((size_t)NB * 4);
    int* bstart    = (int*)alloc((size_t)(NB + 1) * 4);
    (void)ws_size; (void)n_in; (void)out_size;

    // ---- CSR build (no global atomics) ----
    part_count<<<PBLK, 256, 0, stream>>>(ei, E, EN, NB, epb, counts);
    bucket_tot<<<NB, 256, 0, stream>>>(counts, btot);
    bucket_scan<<<1, 256, 0, stream>>>(btot, NB, EN, bstart);
    bucket_base<<<NB, 256, 0, stream>>>(counts, bstart);
    part_scatter<<<PBLK, 256, 0, stream>>>(ei, E, EN, NB, epb, counts, ebuf);
    bucket_csr<<<NB, 256, 0, stream>>>(ebuf, bstart, NB, N, EN, row_start, csr_src);

    // ---- weight conversion ----
    wtrans_kernel<<<(128 * 64 + 255) / 256, 256, 0, stream>>>(W0, WT0, 64, 6);
    wtrans_kernel<<<(128 * 128 + 255) / 256, 256, 0, stream>>>(W1, WT1, 128, 7);
    wtrans_kernel<<<(128 * 128 + 255) / 256, 256, 0, stream>>>(W2, WT2, 128, 7);

    int gemm_grid = (N + 63) / 64;
    int agg_grid  = (N + 3) / 4;
    int n_grid    = (N + 255) / 256;

    // ---- layer 0 (A read fp32 in-kernel) ----
    gemm_mfma<<<gemm_grid, 256, 0, stream>>>(nullptr, x, WT0, as0, ad0, hbuf, als, ald, N, 64);
    agg_kernel<<<agg_grid, 256, 0, stream>>>(hbuf, als, ald, row_start, csr_src, b0, xA, N, 1);

    // ---- layer 1 ----
    gemm_mfma<<<gemm_grid, 256, 0, stream>>>(xA, nullptr, WT1, as1, ad1, hbuf, als, ald, N, 128);
    agg_kernel<<<agg_grid, 256, 0, stream>>>(hbuf, als, ald, row_start, csr_src, b1, xB, N, 1);

    // ---- layer 2 ----
    gemm_mfma<<<gemm_grid, 256, 0, stream>>>(xB, nullptr, WT2, as2, ad2, hbuf, als, ald, N, 128);
    agg_kernel<<<agg_grid, 256, 0, stream>>>(hbuf, als, ald, row_start, csr_src, b2, xA, N, 1);

    // ---- layer 3 ----
    gemm3_kernel<<<n_grid, 256, 0, stream>>>(xA, W3, as3, ad3, h3, als3, ald3, N);
    agg3_kernel<<<n_grid, 256, 0, stream>>>(h3, als3, ald3, row_start, csr_src, b3, out, N);
}

// Round 13
// 448.766 us; speedup vs baseline: 1.0131x; 1.0131x over previous
//
#include <hip/hip_runtime.h>
#include <hip/hip_bf16.h>
#include <hip/hip_fp16.h>

#define IN_CH 64
#define HID 32
#define HEADS 4
#define OUT_CH 6
#define NEG_SLOPE 0.2f

typedef __attribute__((ext_vector_type(8))) _Float16 half8;
typedef __attribute__((ext_vector_type(4))) float f32x4;

// ============== CSR build: bucket-partitioned, LDS-atomic only ==============

#define PBLK 256
#define CAP 6144

__global__ __launch_bounds__(256) void part_count(const int* __restrict__ ei, int E, int EN,
                                                  int NB, int epb, int* __restrict__ counts) {
    __shared__ int cnt[512];
    int b = blockIdx.x, t = threadIdx.x;
    for (int i = t; i < NB; i += 256) cnt[i] = 0;
    __syncthreads();
    int e0 = b * epb;
    int e1 = min(e0 + epb, EN);
    for (int e = e0 + t; e < e1; e += 256) {
        int d = (e < E) ? ei[E + e] : (e - E);
        atomicAdd(&cnt[d >> 8], 1);
    }
    __syncthreads();
    for (int i = t; i < NB; i += 256) counts[(size_t)i * PBLK + b] = cnt[i];
}

__global__ __launch_bounds__(256) void bucket_tot(const int* __restrict__ counts,
                                                  int* __restrict__ btot) {
    __shared__ int red[256];
    int k = blockIdx.x, t = threadIdx.x;
    red[t] = counts[(size_t)k * PBLK + t];
    __syncthreads();
    for (int off = 128; off; off >>= 1) {
        if (t < off) red[t] += red[t + off];
        __syncthreads();
    }
    if (t == 0) btot[k] = red[0];
}

__global__ __launch_bounds__(256) void bucket_scan(const int* __restrict__ btot, int NB, int EN,
                                                   int* __restrict__ bstart) {
    __shared__ int tmp[256];
    int t = threadIdx.x;
    int chunk = (NB + 255) >> 8;
    int s0 = t * chunk, s1 = min(s0 + chunk, NB);
    int sum = 0;
    for (int i = s0; i < s1; ++i) sum += btot[i];
    tmp[t] = sum;
    __syncthreads();
    for (int off = 1; off < 256; off <<= 1) {
        int v = (t >= off) ? tmp[t - off] : 0;
        __syncthreads();
        tmp[t] += v;
        __syncthreads();
    }
    int run = (t == 0) ? 0 : tmp[t - 1];
    for (int i = s0; i < s1; ++i) {
        int c = btot[i];
        bstart[i] = run;
        run += c;
    }
    if (t == 255) bstart[NB] = EN;
}

__global__ __launch_bounds__(256) void bucket_base(int* __restrict__ counts,
                                                   const int* __restrict__ bstart) {
    __shared__ int sc[256];
    int k = blockIdx.x, t = threadIdx.x;
    int v = counts[(size_t)k * PBLK + t];
    sc[t] = v;
    __syncthreads();
    for (int off = 1; off < 256; off <<= 1) {
        int u = (t >= off) ? sc[t - off] : 0;
        __syncthreads();
        sc[t] += u;
        __syncthreads();
    }
    counts[(size_t)k * PBLK + t] = bstart[k] + sc[t] - v;
}

__global__ __launch_bounds__(256) void part_scatter(const int* __restrict__ ei, int E, int EN,
                                                    int NB, int epb,
                                                    const int* __restrict__ base,
                                                    int2* __restrict__ ebuf) {
    __shared__ int cur[512];
    int b = blockIdx.x, t = threadIdx.x;
    for (int i = t; i < NB; i += 256) cur[i] = base[(size_t)i * PBLK + b];
    __syncthreads();
    int e0 = b * epb;
    int e1 = min(e0 + epb, EN);
    for (int e = e0 + t; e < e1; e += 256) {
        int s, d;
        if (e < E) { s = ei[e]; d = ei[E + e]; }
        else       { s = e - E; d = s; }
        int slot = atomicAdd(&cur[d >> 8], 1);
        ebuf[slot] = make_int2(s, d & 255);
    }
}

__global__ __launch_bounds__(256) void bucket_csr(const int2* __restrict__ ebuf,
                                                  const int* __restrict__ bstart,
                                                  int NB, int N, int EN,
                                                  int* __restrict__ row_start,
                                                  int* __restrict__ csr_src) {
    __shared__ int cnt[256];
    __shared__ int sc[256];
    __shared__ int stage[CAP];
    int k = blockIdx.x, t = threadIdx.x;
    int s0 = bstart[k], s1 = bstart[k + 1];
    int len = s1 - s0;
    cnt[t] = 0;
    __syncthreads();
    for (int i = t; i < len; i += 256) atomicAdd(&cnt[ebuf[s0 + i].y], 1);
    __syncthreads();
    int v = cnt[t];
    sc[t] = v;
    __syncthreads();
    for (int off = 1; off < 256; off <<= 1) {
        int u = (t >= off) ? sc[t - off] : 0;
        __syncthreads();
        sc[t] += u;
        __syncthreads();
    }
    int excl = sc[t] - v;
    int g = (k << 8) + t;
    if (g < N) row_start[g] = s0 + excl;
    if (k == NB - 1 && t == 0) row_start[N] = EN;
    bool fits = (len <= CAP);
    cnt[t] = fits ? excl : s0 + excl;
    __syncthreads();
    if (fits) {
        for (int i = t; i < len; i += 256) {
            int2 e = ebuf[s0 + i];
            int slot = atomicAdd(&cnt[e.y], 1);
            stage[slot] = e.x;
        }
        __syncthreads();
        for (int i = t; i < len; i += 256) csr_src[s0 + i] = stage[i];
    } else {
        for (int i = t; i < len; i += 256) {
            int2 e = ebuf[s0 + i];
            int slot = atomicAdd(&cnt[e.y], 1);
            csr_src[slot] = e.x;
        }
    }
}

// ---------------- weight transpose ----------------

__global__ void wtrans_kernel(const float* __restrict__ W, __half* __restrict__ WT,
                              int K, int kshift) {
    int o = blockIdx.x * blockDim.x + threadIdx.x;
    if (o >= (K << 7)) return;
    int c = o >> kshift;
    int k = o & (K - 1);
    WT[o] = __float2half(W[(size_t)k * 128 + c]);
}

// ------- MFMA GEMM: C[N][128](fp16) = A[N][K] @ W, + als/ald -------

__global__ __launch_bounds__(256) void gemm_mfma(const __half* __restrict__ A,
                                                 const float* __restrict__ Af,
                                                 const __half* __restrict__ WT,
                                                 const float* __restrict__ avs,
                                                 const float* __restrict__ avd,
                                                 __half* __restrict__ C,
                                                 float* __restrict__ als,
                                                 float* __restrict__ ald,
                                                 int N, int K) {
    int tid = threadIdx.x;
    int wv = tid >> 6, lane = tid & 63;
    int row0 = blockIdx.x * 64 + wv * 16;
    int lrow = lane & 15;
    int lk = (lane >> 4) * 8;
    int garow = row0 + lrow;

    half8 afrag[4];
#pragma unroll
    for (int ks = 0; ks < 4; ++ks) {
        half8 z = {(_Float16)0, (_Float16)0, (_Float16)0, (_Float16)0,
                   (_Float16)0, (_Float16)0, (_Float16)0, (_Float16)0};
        afrag[ks] = z;
    }
    if (garow < N) {
        if (K == 128) {
            const __half* ap = A + (size_t)garow * 128 + lk;
#pragma unroll
            for (int ks = 0; ks < 4; ++ks)
                afrag[ks] = *reinterpret_cast<const half8*>(ap + ks * 32);
        } else {
            const float* ap = Af + (size_t)garow * 64 + lk;
#pragma unroll
            for (int ks = 0; ks < 2; ++ks) {
                float4 f0 = *reinterpret_cast<const float4*>(ap + ks * 32);
                float4 f1 = *reinterpret_cast<const float4*>(ap + ks * 32 + 4);
                half8 fr = {(_Float16)f0.x, (_Float16)f0.y, (_Float16)f0.z, (_Float16)f0.w,
                            (_Float16)f1.x, (_Float16)f1.y, (_Float16)f1.z, (_Float16)f1.w};
                afrag[ks] = fr;
            }
        }
    }

    f32x4 acc[8];
#pragma unroll
    for (int t = 0; t < 8; ++t) acc[t] = (f32x4){0.f, 0.f, 0.f, 0.f};

#pragma unroll
    for (int t = 0; t < 8; ++t) {
        const __half* wb = WT + (size_t)(t * 16 + lrow) * K + lk;
        if (K == 128) {
#pragma unroll
            for (int ks = 0; ks < 4; ++ks) {
                half8 bfrag = *reinterpret_cast<const half8*>(wb + ks * 32);
                acc[t] = __builtin_amdgcn_mfma_f32_16x16x32_f16(afrag[ks], bfrag, acc[t], 0, 0, 0);
            }
        } else {
#pragma unroll
            for (int ks = 0; ks < 2; ++ks) {
                half8 bfrag = *reinterpret_cast<const half8*>(wb + ks * 32);
                acc[t] = __builtin_amdgcn_mfma_f32_16x16x32_f16(afrag[ks], bfrag, acc[t], 0, 0, 0);
            }
        }
    }

    int rbase = (lane >> 4) * 4;
#pragma unroll
    for (int t = 0; t < 8; ++t) {
#pragma unroll
        for (int j = 0; j < 4; ++j) {
            int gr = row0 + rbase + j;
            if (gr < N) C[(size_t)gr * 128 + t * 16 + lrow] = __float2half(acc[t][j]);
        }
    }
    float ps[4][4], pd[4][4];
#pragma unroll
    for (int h = 0; h < 4; ++h)
#pragma unroll
        for (int j = 0; j < 4; ++j) { ps[h][j] = 0.f; pd[h][j] = 0.f; }
#pragma unroll
    for (int t = 0; t < 8; ++t) {
        int ht = t >> 1;
        float as_c = avs[t * 16 + lrow];
        float ad_c = avd[t * 16 + lrow];
#pragma unroll
        for (int j = 0; j < 4; ++j) {
            ps[ht][j] += acc[t][j] * as_c;
            pd[ht][j] += acc[t][j] * ad_c;
        }
    }
#pragma unroll
    for (int h = 0; h < 4; ++h) {
#pragma unroll
        for (int j = 0; j < 4; ++j) {
            float s = ps[h][j], d = pd[h][j];
            s += __shfl_xor(s, 1); d += __shfl_xor(d, 1);
            s += __shfl_xor(s, 2); d += __shfl_xor(d, 2);
            s += __shfl_xor(s, 4); d += __shfl_xor(d, 4);
            s += __shfl_xor(s, 8); d += __shfl_xor(d, 8);
            if (lrow == 0) {
                int gr = row0 + rbase + j;
                if (gr < N) {
                    als[(size_t)gr * 4 + h] = s;
                    ald[(size_t)gr * 4 + h] = d;
                }
            }
        }
    }
}

// ------- wave-per-node aggregation (layers 0-2), fp16 h — R11 flat form -------
// Flat single-stream loop; half-wave lanes share an edge (uniform csr/als
// broadcasts, redundant exp in-register); each lane owns a 4-dim slice ->
// one 8B uint2 load per edge row slice. Unroll x4 per half.

__device__ __forceinline__ float lrelu(float x) { return x > 0.f ? x : NEG_SLOPE * x; }

__global__ __launch_bounds__(256) void agg_kernel(const __half* __restrict__ h,
                                                  const float* __restrict__ als4,
                                                  const float* __restrict__ ald4,
                                                  const int* __restrict__ row_start,
                                                  const int* __restrict__ csr_src,
                                                  const float* __restrict__ bias,
                                                  __half* __restrict__ xout,
                                                  int N, int applyElu) {
    int v = (int)((blockIdx.x * blockDim.x + threadIdx.x) >> 6);
    int lane = threadIdx.x & 63;
    if (v >= N) return;
    int base = row_start[v], end = row_start[v + 1];

    int half_ = lane >> 5;
    int dim4 = (lane & 31) * 4;
    int hd2  = (lane & 31) >> 3;

    float aldh = ald4[(size_t)v * 4 + hd2];
    float alsh = als4[(size_t)v * 4 + hd2];
    float em = lrelu(alsh + aldh);
    const __half* hdim = h + dim4;
    const float* alsb = als4 + hd2;

    float4 acc  = make_float4(0.f, 0.f, 0.f, 0.f);
    float4 acc2 = make_float4(0.f, 0.f, 0.f, 0.f);
    float ssum = 0.f, ssum2 = 0.f;

    int j = base + half_;
    for (; j + 6 < end; j += 8) {
        int s0 = csr_src[j + 0];
        int s1 = csr_src[j + 2];
        int s2 = csr_src[j + 4];
        int s3 = csr_src[j + 6];
        float a0 = alsb[(size_t)s0 * 4];
        float a1 = alsb[(size_t)s1 * 4];
        float a2 = alsb[(size_t)s2 * 4];
        float a3 = alsb[(size_t)s3 * 4];
        uint2 r0 = *reinterpret_cast<const uint2*>(hdim + (size_t)s0 * 128);
        uint2 r1 = *reinterpret_cast<const uint2*>(hdim + (size_t)s1 * 128);
        uint2 r2 = *reinterpret_cast<const uint2*>(hdim + (size_t)s2 * 128);
        uint2 r3 = *reinterpret_cast<const uint2*>(hdim + (size_t)s3 * 128);
        float e0 = __expf(lrelu(a0 + aldh) - em);
        float e1 = __expf(lrelu(a1 + aldh) - em);
        float e2 = __expf(lrelu(a2 + aldh) - em);
        float e3 = __expf(lrelu(a3 + aldh) - em);
        ssum  += e0 + e2;
        ssum2 += e1 + e3;
        float2 f0a = __half22float2(*reinterpret_cast<__half2*>(&r0.x));
        float2 f0b = __half22float2(*reinterpret_cast<__half2*>(&r0.y));
        float2 f1a = __half22float2(*reinterpret_cast<__half2*>(&r1.x));
        float2 f1b = __half22float2(*reinterpret_cast<__half2*>(&r1.y));
        float2 f2a = __half22float2(*reinterpret_cast<__half2*>(&r2.x));
        float2 f2b = __half22float2(*reinterpret_cast<__half2*>(&r2.y));
        float2 f3a = __half22float2(*reinterpret_cast<__half2*>(&r3.x));
        float2 f3b = __half22float2(*reinterpret_cast<__half2*>(&r3.y));
        acc.x  += e0 * f0a.x; acc.y  += e0 * f0a.y; acc.z  += e0 * f0b.x; acc.w  += e0 * f0b.y;
        acc2.x += e1 * f1a.x; acc2.y += e1 * f1a.y; acc2.z += e1 * f1b.x; acc2.w += e1 * f1b.y;
        acc.x  += e2 * f2a.x; acc.y  += e2 * f2a.y; acc.z  += e2 * f2b.x; acc.w  += e2 * f2b.y;
        acc2.x += e3 * f3a.x; acc2.y += e3 * f3a.y; acc2.z += e3 * f3b.x; acc2.w += e3 * f3b.y;
    }
    for (; j < end; j += 2) {
        int s0 = csr_src[j];
        float a0 = alsb[(size_t)s0 * 4];
        uint2 r0 = *reinterpret_cast<const uint2*>(hdim + (size_t)s0 * 128);
        float e0 = __expf(lrelu(a0 + aldh) - em);
        ssum += e0;
        float2 f0a = __half22float2(*reinterpret_cast<__half2*>(&r0.x));
        float2 f0b = __half22float2(*reinterpret_cast<__half2*>(&r0.y));
        acc.x += e0 * f0a.x; acc.y += e0 * f0a.y; acc.z += e0 * f0b.x; acc.w += e0 * f0b.y;
    }
    acc.x += acc2.x; acc.y += acc2.y; acc.z += acc2.z; acc.w += acc2.w;
    ssum += ssum2;
    acc.x += __shfl_xor(acc.x, 32);
    acc.y += __shfl_xor(acc.y, 32);
    acc.z += __shfl_xor(acc.z, 32);
    acc.w += __shfl_xor(acc.w, 32);
    ssum  += __shfl_xor(ssum, 32);

    if (lane < 32) {
        float inv = 1.0f / (ssum + 1e-16f);
        float4 bv = *reinterpret_cast<const float4*>(bias + dim4);
        float4 o;
        o.x = acc.x * inv + bv.x;
        o.y = acc.y * inv + bv.y;
        o.z = acc.z * inv + bv.z;
        o.w = acc.w * inv + bv.w;
        if (applyElu) {
            o.x = o.x > 0.f ? o.x : expm1f(o.x);
            o.y = o.y > 0.f ? o.y : expm1f(o.y);
            o.z = o.z > 0.f ? o.z : expm1f(o.z);
            o.w = o.w > 0.f ? o.w : expm1f(o.w);
        }
        __half2* op = reinterpret_cast<__half2*>(xout + (size_t)v * 128 + dim4);
        op[0] = __float22half2_rn(make_float2(o.x, o.y));
        op[1] = __float22half2_rn(make_float2(o.z, o.w));
    }
}

// ---------------- layer 3: GEMM [N,128]x[128,6] -> padded h3p[N][8] ----------------

__global__ void gemm3_kernel(const __half* __restrict__ x, const float* __restrict__ W,
                             const float* __restrict__ as3, const float* __restrict__ ad3,
                             float* __restrict__ h3p, float* __restrict__ als3,
                             float* __restrict__ ald3, int N) {
    int n = blockIdx.x * blockDim.x + threadIdx.x;
    if (n >= N) return;
    float acc[6] = {0.f, 0.f, 0.f, 0.f, 0.f, 0.f};
    const __half* xp = x + (size_t)n * 128;
#pragma unroll 2
    for (int k8 = 0; k8 < 16; ++k8) {
        union { uint4 u; __half hh[8]; } rv;
        rv.u = *reinterpret_cast<const uint4*>(xp + k8 * 8);
        const float* w0 = W + (size_t)(k8 * 8) * 6;
#pragma unroll
        for (int kk = 0; kk < 8; ++kk) {
            float xv = (float)rv.hh[kk];
#pragma unroll
            for (int q = 0; q < 6; ++q)
                acc[q] += xv * w0[kk * 6 + q];
        }
    }
    float s = 0.f, d = 0.f;
#pragma unroll
    for (int q = 0; q < 6; ++q) {
        s += acc[q] * as3[q];
        d += acc[q] * ad3[q];
    }
    float4* hp = reinterpret_cast<float4*>(h3p + (size_t)n * 8);
    hp[0] = make_float4(acc[0], acc[1], acc[2], acc[3]);
    hp[1] = make_float4(acc[4], acc[5], 0.f, 0.f);
    als3[n] = s;
    ald3[n] = d;
}

// ---- final aggregation v2: 32 lanes/node = 4 edge-slots x 8 dims ----
// Per edge: uniform csr/als3 broadcast + one coalesced 32B h3p row read.
// Slot-reduce via shfl_xor(8,16).

__global__ __launch_bounds__(256) void agg3_kernel(const float* __restrict__ h3p,
                                                   const float* __restrict__ als3,
                                                   const float* __restrict__ ald3,
                                                   const int* __restrict__ row_start,
                                                   const int* __restrict__ csr_src,
                                                   const float* __restrict__ b3,
                                                   float* __restrict__ out, int N) {
    int v = (int)((blockIdx.x * blockDim.x + threadIdx.x) >> 5);
    int lane = threadIdx.x & 31;
    if (v >= N) return;
    int base = row_start[v], end = row_start[v + 1];
    int slot = lane >> 3;       // 0..3: parallel edges
    int dim  = lane & 7;        // 0..7: h3p column

    float aldv = ald3[v];
    float em = lrelu(als3[v] + aldv);
    float acc = 0.f, ssum = 0.f;

    for (int j = base + slot; j < end; j += 4) {
        int s = csr_src[j];
        float a = als3[s];
        float hv = h3p[(size_t)s * 8 + dim];
        float e = __expf(lrelu(a + aldv) - em);
        ssum += e;
        acc += e * hv;
    }
    // reduce over slots (bits 3,4 of lane); dim preserved
    acc  += __shfl_xor(acc, 8);
    acc  += __shfl_xor(acc, 16);
    ssum += __shfl_xor(ssum, 8);
    ssum += __shfl_xor(ssum, 16);

    if (slot == 0 && dim < 6) {
        float inv = 1.f / (ssum + 1e-16f);
        out[(size_t)v * 6 + dim] = acc * inv + b3[dim];
    }
}

// ---------------- launch ----------------

extern "C" void kernel_launch(void* const* d_in, const int* in_sizes, int n_in,
                              void* d_out, int out_size, void* d_ws, size_t ws_size,
                              hipStream_t stream) {
    const float* x    = (const float*)d_in[0];
    const int*   ei   = (const int*)d_in[1];
    const float* W0   = (const float*)d_in[3];
    const float* as0  = (const float*)d_in[4];
    const float* ad0  = (const float*)d_in[5];
    const float* b0   = (const float*)d_in[6];
    const float* W1   = (const float*)d_in[7];
    const float* as1  = (const float*)d_in[8];
    const float* ad1  = (const float*)d_in[9];
    const float* b1   = (const float*)d_in[10];
    const float* W2   = (const float*)d_in[11];
    const float* as2  = (const float*)d_in[12];
    const float* ad2  = (const float*)d_in[13];
    const float* b2   = (const float*)d_in[14];
    const float* W3   = (const float*)d_in[15];
    const float* as3  = (const float*)d_in[16];
    const float* ad3  = (const float*)d_in[17];
    const float* b3   = (const float*)d_in[18];
    float* out = (float*)d_out;

    int N = in_sizes[0] / IN_CH;
    int E = in_sizes[1] / 2;
    int EN = E + N;
    int NB = (N + 255) >> 8;
    int epb = (EN + PBLK - 1) / PBLK;

    char* p = (char*)d_ws;
    auto alloc = [&](size_t bytes) {
        char* q = p;
        p += (bytes + 255) & ~(size_t)255;
        return q;
    };
    __half* hbuf = (__half*)alloc((size_t)N * 128 * 2);
    __half* xA   = (__half*)alloc((size_t)N * 128 * 2);
    __half* xB   = (__half*)alloc((size_t)N * 128 * 2);
    __half* WT0  = (__half*)alloc((size_t)128 * 64 * 2);
    __half* WT1  = (__half*)alloc((size_t)128 * 128 * 2);
    __half* WT2  = (__half*)alloc((size_t)128 * 128 * 2);
    float* als  = (float*)alloc((size_t)N * 4 * 4);
    float* ald  = (float*)alloc((size_t)N * 4 * 4);
    float* h3p  = (float*)alloc((size_t)N * 8 * 4);
    float* als3 = (float*)alloc((size_t)N * 4);
    float* ald3 = (float*)alloc((size_t)N * 4);
    int* row_start = (int*)alloc((size_t)(N + 1) * 4);
    int* csr_src   = (int*)alloc((size_t)EN * 4);
    int2* ebuf     = (int2*)alloc((size_t)EN * 8);
    int* counts    = (int*)alloc((size_t)NB * PBLK * 4);
    int* btot      = (int*)alloc((size_t)NB * 4);
    int* bstart    = (int*)alloc((size_t)(NB + 1) * 4);
    (void)ws_size; (void)n_in; (void)out_size;

    // ---- CSR build (no global atomics) ----
    part_count<<<PBLK, 256, 0, stream>>>(ei, E, EN, NB, epb, counts);
    bucket_tot<<<NB, 256, 0, stream>>>(counts, btot);
    bucket_scan<<<1, 256, 0, stream>>>(btot, NB, EN, bstart);
    bucket_base<<<NB, 256, 0, stream>>>(counts, bstart);
    part_scatter<<<PBLK, 256, 0, stream>>>(ei, E, EN, NB, epb, counts, ebuf);
    bucket_csr<<<NB, 256, 0, stream>>>(ebuf, bstart, NB, N, EN, row_start, csr_src);

    // ---- weight conversion ----
    wtrans_kernel<<<(128 * 64 + 255) / 256, 256, 0, stream>>>(W0, WT0, 64, 6);
    wtrans_kernel<<<(128 * 128 + 255) / 256, 256, 0, stream>>>(W1, WT1, 128, 7);
    wtrans_kernel<<<(128 * 128 + 255) / 256, 256, 0, stream>>>(W2, WT2, 128, 7);

    int gemm_grid = (N + 63) / 64;
    int agg_grid  = (N + 3) / 4;
    int n_grid    = (N + 255) / 256;
    int agg3_grid = (N + 7) / 8;

    // ---- layer 0 (A read fp32 in-kernel) ----
    gemm_mfma<<<gemm_grid, 256, 0, stream>>>(nullptr, x, WT0, as0, ad0, hbuf, als, ald, N, 64);
    agg_kernel<<<agg_grid, 256, 0, stream>>>(hbuf, als, ald, row_start, csr_src, b0, xA, N, 1);

    // ---- layer 1 ----
    gemm_mfma<<<gemm_grid, 256, 0, stream>>>(xA, nullptr, WT1, as1, ad1, hbuf, als, ald, N, 128);
    agg_kernel<<<agg_grid, 256, 0, stream>>>(hbuf, als, ald, row_start, csr_src, b1, xB, N, 1);

    // ---- layer 2 ----
    gemm_mfma<<<gemm_grid, 256, 0, stream>>>(xB, nullptr, WT2, as2, ad2, hbuf, als, ald, N, 128);
    agg_kernel<<<agg_grid, 256, 0, stream>>>(hbuf, als, ald, row_start, csr_src, b2, xA, N, 1);

    // ---- layer 3 ----
    gemm3_kernel<<<n_grid, 256, 0, stream>>>(xA, W3, as3, ad3, h3p, als3, ald3, N);
    agg3_kernel<<<agg3_grid, 256, 0, stream>>>(h3p, als3, ald3, row_start, csr_src, b3, out, N);
}

// Round 14
// 443.267 us; speedup vs baseline: 1.0257x; 1.0124x over previous
//
#include <hip/hip_runtime.h>
#include <hip/hip_bf16.h>
#include <hip/hip_fp16.h>

#define IN_CH 64
#define HID 32
#define HEADS 4
#define OUT_CH 6
#define NEG_SLOPE 0.2f

typedef __attribute__((ext_vector_type(8))) _Float16 half8;
typedef __attribute__((ext_vector_type(4))) float f32x4;

// ============== CSR build: bucket-partitioned, LDS-atomic only ==============

#define PBLK 256
#define CAP 6144

__global__ __launch_bounds__(256) void part_count(const int* __restrict__ ei, int E, int EN,
                                                  int NB, int epb, int* __restrict__ counts) {
    __shared__ int cnt[512];
    int b = blockIdx.x, t = threadIdx.x;
    for (int i = t; i < NB; i += 256) cnt[i] = 0;
    __syncthreads();
    int e0 = b * epb;
    int e1 = min(e0 + epb, EN);
    for (int e = e0 + t; e < e1; e += 256) {
        int d = (e < E) ? ei[E + e] : (e - E);
        atomicAdd(&cnt[d >> 8], 1);
    }
    __syncthreads();
    for (int i = t; i < NB; i += 256) counts[(size_t)i * PBLK + b] = cnt[i];
}

__global__ __launch_bounds__(256) void bucket_tot(const int* __restrict__ counts,
                                                  int* __restrict__ btot) {
    __shared__ int red[256];
    int k = blockIdx.x, t = threadIdx.x;
    red[t] = counts[(size_t)k * PBLK + t];
    __syncthreads();
    for (int off = 128; off; off >>= 1) {
        if (t < off) red[t] += red[t + off];
        __syncthreads();
    }
    if (t == 0) btot[k] = red[0];
}

__global__ __launch_bounds__(256) void bucket_scan(const int* __restrict__ btot, int NB, int EN,
                                                   int* __restrict__ bstart) {
    __shared__ int tmp[256];
    int t = threadIdx.x;
    int chunk = (NB + 255) >> 8;
    int s0 = t * chunk, s1 = min(s0 + chunk, NB);
    int sum = 0;
    for (int i = s0; i < s1; ++i) sum += btot[i];
    tmp[t] = sum;
    __syncthreads();
    for (int off = 1; off < 256; off <<= 1) {
        int v = (t >= off) ? tmp[t - off] : 0;
        __syncthreads();
        tmp[t] += v;
        __syncthreads();
    }
    int run = (t == 0) ? 0 : tmp[t - 1];
    for (int i = s0; i < s1; ++i) {
        int c = btot[i];
        bstart[i] = run;
        run += c;
    }
    if (t == 255) bstart[NB] = EN;
}

__global__ __launch_bounds__(256) void bucket_base(int* __restrict__ counts,
                                                   const int* __restrict__ bstart) {
    __shared__ int sc[256];
    int k = blockIdx.x, t = threadIdx.x;
    int v = counts[(size_t)k * PBLK + t];
    sc[t] = v;
    __syncthreads();
    for (int off = 1; off < 256; off <<= 1) {
        int u = (t >= off) ? sc[t - off] : 0;
        __syncthreads();
        sc[t] += u;
        __syncthreads();
    }
    counts[(size_t)k * PBLK + t] = bstart[k] + sc[t] - v;
}

__global__ __launch_bounds__(256) void part_scatter(const int* __restrict__ ei, int E, int EN,
                                                    int NB, int epb,
                                                    const int* __restrict__ base,
                                                    int2* __restrict__ ebuf) {
    __shared__ int cur[512];
    int b = blockIdx.x, t = threadIdx.x;
    for (int i = t; i < NB; i += 256) cur[i] = base[(size_t)i * PBLK + b];
    __syncthreads();
    int e0 = b * epb;
    int e1 = min(e0 + epb, EN);
    for (int e = e0 + t; e < e1; e += 256) {
        int s, d;
        if (e < E) { s = ei[e]; d = ei[E + e]; }
        else       { s = e - E; d = s; }
        int slot = atomicAdd(&cur[d >> 8], 1);
        ebuf[slot] = make_int2(s, d & 255);
    }
}

__global__ __launch_bounds__(256) void bucket_csr(const int2* __restrict__ ebuf,
                                                  const int* __restrict__ bstart,
                                                  int NB, int N, int EN,
                                                  int* __restrict__ row_start,
                                                  int* __restrict__ csr_src) {
    __shared__ int cnt[256];
    __shared__ int sc[256];
    __shared__ int stage[CAP];
    int k = blockIdx.x, t = threadIdx.x;
    int s0 = bstart[k], s1 = bstart[k + 1];
    int len = s1 - s0;
    cnt[t] = 0;
    __syncthreads();
    for (int i = t; i < len; i += 256) atomicAdd(&cnt[ebuf[s0 + i].y], 1);
    __syncthreads();
    int v = cnt[t];
    sc[t] = v;
    __syncthreads();
    for (int off = 1; off < 256; off <<= 1) {
        int u = (t >= off) ? sc[t - off] : 0;
        __syncthreads();
        sc[t] += u;
        __syncthreads();
    }
    int excl = sc[t] - v;
    int g = (k << 8) + t;
    if (g < N) row_start[g] = s0 + excl;
    if (k == NB - 1 && t == 0) row_start[N] = EN;
    bool fits = (len <= CAP);
    cnt[t] = fits ? excl : s0 + excl;
    __syncthreads();
    if (fits) {
        for (int i = t; i < len; i += 256) {
            int2 e = ebuf[s0 + i];
            int slot = atomicAdd(&cnt[e.y], 1);
            stage[slot] = e.x;
        }
        __syncthreads();
        for (int i = t; i < len; i += 256) csr_src[s0 + i] = stage[i];
    } else {
        for (int i = t; i < len; i += 256) {
            int2 e = ebuf[s0 + i];
            int slot = atomicAdd(&cnt[e.y], 1);
            csr_src[slot] = e.x;
        }
    }
}

// ---------------- merged weight transpose (all 3 layers, 1 launch) ----------------

__global__ void wtrans_all(const float* __restrict__ W0, const float* __restrict__ W1,
                           const float* __restrict__ W2, __half* __restrict__ WT0,
                           __half* __restrict__ WT1, __half* __restrict__ WT2) {
    int o = blockIdx.x * blockDim.x + threadIdx.x;
    if (o < 8192) {                      // W0: 64x128 -> WT0[c][k], K=64
        int c = o >> 6, k = o & 63;
        WT0[o] = __float2half(W0[(size_t)k * 128 + c]);
    } else if (o < 8192 + 16384) {       // W1: 128x128
        int i = o - 8192;
        int c = i >> 7, k = i & 127;
        WT1[i] = __float2half(W1[(size_t)k * 128 + c]);
    } else if (o < 8192 + 32768) {       // W2: 128x128
        int i = o - 8192 - 16384;
        int c = i >> 7, k = i & 127;
        WT2[i] = __float2half(W2[(size_t)k * 128 + c]);
    }
}

// ------- MFMA GEMM: C[N][128](fp16) = A[N][K] @ W, + als/ald -------

__global__ __launch_bounds__(256) void gemm_mfma(const __half* __restrict__ A,
                                                 const float* __restrict__ Af,
                                                 const __half* __restrict__ WT,
                                                 const float* __restrict__ avs,
                                                 const float* __restrict__ avd,
                                                 __half* __restrict__ C,
                                                 float* __restrict__ als,
                                                 float* __restrict__ ald,
                                                 int N, int K) {
    int tid = threadIdx.x;
    int wv = tid >> 6, lane = tid & 63;
    int row0 = blockIdx.x * 64 + wv * 16;
    int lrow = lane & 15;
    int lk = (lane >> 4) * 8;
    int garow = row0 + lrow;

    half8 afrag[4];
#pragma unroll
    for (int ks = 0; ks < 4; ++ks) {
        half8 z = {(_Float16)0, (_Float16)0, (_Float16)0, (_Float16)0,
                   (_Float16)0, (_Float16)0, (_Float16)0, (_Float16)0};
        afrag[ks] = z;
    }
    if (garow < N) {
        if (K == 128) {
            const __half* ap = A + (size_t)garow * 128 + lk;
#pragma unroll
            for (int ks = 0; ks < 4; ++ks)
                afrag[ks] = *reinterpret_cast<const half8*>(ap + ks * 32);
        } else {
            const float* ap = Af + (size_t)garow * 64 + lk;
#pragma unroll
            for (int ks = 0; ks < 2; ++ks) {
                float4 f0 = *reinterpret_cast<const float4*>(ap + ks * 32);
                float4 f1 = *reinterpret_cast<const float4*>(ap + ks * 32 + 4);
                half8 fr = {(_Float16)f0.x, (_Float16)f0.y, (_Float16)f0.z, (_Float16)f0.w,
                            (_Float16)f1.x, (_Float16)f1.y, (_Float16)f1.z, (_Float16)f1.w};
                afrag[ks] = fr;
            }
        }
    }

    f32x4 acc[8];
#pragma unroll
    for (int t = 0; t < 8; ++t) acc[t] = (f32x4){0.f, 0.f, 0.f, 0.f};

#pragma unroll
    for (int t = 0; t < 8; ++t) {
        const __half* wb = WT + (size_t)(t * 16 + lrow) * K + lk;
        if (K == 128) {
#pragma unroll
            for (int ks = 0; ks < 4; ++ks) {
                half8 bfrag = *reinterpret_cast<const half8*>(wb + ks * 32);
                acc[t] = __builtin_amdgcn_mfma_f32_16x16x32_f16(afrag[ks], bfrag, acc[t], 0, 0, 0);
            }
        } else {
#pragma unroll
            for (int ks = 0; ks < 2; ++ks) {
                half8 bfrag = *reinterpret_cast<const half8*>(wb + ks * 32);
                acc[t] = __builtin_amdgcn_mfma_f32_16x16x32_f16(afrag[ks], bfrag, acc[t], 0, 0, 0);
            }
        }
    }

    int rbase = (lane >> 4) * 4;
#pragma unroll
    for (int t = 0; t < 8; ++t) {
#pragma unroll
        for (int j = 0; j < 4; ++j) {
            int gr = row0 + rbase + j;
            if (gr < N) C[(size_t)gr * 128 + t * 16 + lrow] = __float2half(acc[t][j]);
        }
    }
    float ps[4][4], pd[4][4];
#pragma unroll
    for (int h = 0; h < 4; ++h)
#pragma unroll
        for (int j = 0; j < 4; ++j) { ps[h][j] = 0.f; pd[h][j] = 0.f; }
#pragma unroll
    for (int t = 0; t < 8; ++t) {
        int ht = t >> 1;
        float as_c = avs[t * 16 + lrow];
        float ad_c = avd[t * 16 + lrow];
#pragma unroll
        for (int j = 0; j < 4; ++j) {
            ps[ht][j] += acc[t][j] * as_c;
            pd[ht][j] += acc[t][j] * ad_c;
        }
    }
#pragma unroll
    for (int h = 0; h < 4; ++h) {
#pragma unroll
        for (int j = 0; j < 4; ++j) {
            float s = ps[h][j], d = pd[h][j];
            s += __shfl_xor(s, 1); d += __shfl_xor(d, 1);
            s += __shfl_xor(s, 2); d += __shfl_xor(d, 2);
            s += __shfl_xor(s, 4); d += __shfl_xor(d, 4);
            s += __shfl_xor(s, 8); d += __shfl_xor(d, 8);
            if (lrow == 0) {
                int gr = row0 + rbase + j;
                if (gr < N) {
                    als[(size_t)gr * 4 + h] = s;
                    ald[(size_t)gr * 4 + h] = d;
                }
            }
        }
    }
}

// ------- wave-per-node aggregation (layers 0-2), fp16 h — flat form -------
// R11 structure; address math in 32-bit byte offsets (SGPR-base + voffset),
// scalar (float)half casts in the FMA (v_fma_mix) instead of cvt_pk pairs.

__device__ __forceinline__ float lrelu(float x) { return x > 0.f ? x : NEG_SLOPE * x; }

__global__ __launch_bounds__(256) void agg_kernel(const __half* __restrict__ h,
                                                  const float* __restrict__ als4,
                                                  const float* __restrict__ ald4,
                                                  const int* __restrict__ row_start,
                                                  const int* __restrict__ csr_src,
                                                  const float* __restrict__ bias,
                                                  __half* __restrict__ xout,
                                                  int N, int applyElu) {
    int v = (int)((blockIdx.x * blockDim.x + threadIdx.x) >> 6);
    int lane = threadIdx.x & 63;
    if (v >= N) return;
    int base = row_start[v], end = row_start[v + 1];

    int half_ = lane >> 5;
    int dim4 = (lane & 31) * 4;
    int hd2  = (lane & 31) >> 3;

    float aldh = ald4[(size_t)v * 4 + hd2];
    float alsh = als4[(size_t)v * 4 + hd2];
    float em = lrelu(alsh + aldh);

    const char* hB = (const char*)h;
    const char* aB = (const char*)als4;
    unsigned dby = (unsigned)dim4 * 2;       // byte offset into 256B h row
    unsigned aby = (unsigned)hd2 * 4;        // byte offset into 16B als row

    float4 acc  = make_float4(0.f, 0.f, 0.f, 0.f);
    float4 acc2 = make_float4(0.f, 0.f, 0.f, 0.f);
    float ssum = 0.f, ssum2 = 0.f;

    union H4 { uint2 u; __half hh[4]; };

    int j = base + half_;
    for (; j + 6 < end; j += 8) {
        unsigned s0 = (unsigned)csr_src[j + 0];
        unsigned s1 = (unsigned)csr_src[j + 2];
        unsigned s2 = (unsigned)csr_src[j + 4];
        unsigned s3 = (unsigned)csr_src[j + 6];
        float a0 = *(const float*)(aB + (s0 << 4) + aby);
        float a1 = *(const float*)(aB + (s1 << 4) + aby);
        float a2 = *(const float*)(aB + (s2 << 4) + aby);
        float a3 = *(const float*)(aB + (s3 << 4) + aby);
        H4 r0, r1, r2, r3;
        r0.u = *(const uint2*)(hB + (s0 << 8) + dby);
        r1.u = *(const uint2*)(hB + (s1 << 8) + dby);
        r2.u = *(const uint2*)(hB + (s2 << 8) + dby);
        r3.u = *(const uint2*)(hB + (s3 << 8) + dby);
        float e0 = __expf(lrelu(a0 + aldh) - em);
        float e1 = __expf(lrelu(a1 + aldh) - em);
        float e2 = __expf(lrelu(a2 + aldh) - em);
        float e3 = __expf(lrelu(a3 + aldh) - em);
        ssum  += e0 + e2;
        ssum2 += e1 + e3;
        acc.x  += e0 * (float)r0.hh[0]; acc.y  += e0 * (float)r0.hh[1];
        acc.z  += e0 * (float)r0.hh[2]; acc.w  += e0 * (float)r0.hh[3];
        acc2.x += e1 * (float)r1.hh[0]; acc2.y += e1 * (float)r1.hh[1];
        acc2.z += e1 * (float)r1.hh[2]; acc2.w += e1 * (float)r1.hh[3];
        acc.x  += e2 * (float)r2.hh[0]; acc.y  += e2 * (float)r2.hh[1];
        acc.z  += e2 * (float)r2.hh[2]; acc.w  += e2 * (float)r2.hh[3];
        acc2.x += e3 * (float)r3.hh[0]; acc2.y += e3 * (float)r3.hh[1];
        acc2.z += e3 * (float)r3.hh[2]; acc2.w += e3 * (float)r3.hh[3];
    }
    for (; j < end; j += 2) {
        unsigned s0 = (unsigned)csr_src[j];
        float a0 = *(const float*)(aB + (s0 << 4) + aby);
        H4 r0;
        r0.u = *(const uint2*)(hB + (s0 << 8) + dby);
        float e0 = __expf(lrelu(a0 + aldh) - em);
        ssum += e0;
        acc.x += e0 * (float)r0.hh[0]; acc.y += e0 * (float)r0.hh[1];
        acc.z += e0 * (float)r0.hh[2]; acc.w += e0 * (float)r0.hh[3];
    }
    acc.x += acc2.x; acc.y += acc2.y; acc.z += acc2.z; acc.w += acc2.w;
    ssum += ssum2;
    acc.x += __shfl_xor(acc.x, 32);
    acc.y += __shfl_xor(acc.y, 32);
    acc.z += __shfl_xor(acc.z, 32);
    acc.w += __shfl_xor(acc.w, 32);
    ssum  += __shfl_xor(ssum, 32);

    if (lane < 32) {
        float inv = 1.0f / (ssum + 1e-16f);
        float4 bv = *reinterpret_cast<const float4*>(bias + dim4);
        float4 o;
        o.x = acc.x * inv + bv.x;
        o.y = acc.y * inv + bv.y;
        o.z = acc.z * inv + bv.z;
        o.w = acc.w * inv + bv.w;
        if (applyElu) {
            o.x = o.x > 0.f ? o.x : expm1f(o.x);
            o.y = o.y > 0.f ? o.y : expm1f(o.y);
            o.z = o.z > 0.f ? o.z : expm1f(o.z);
            o.w = o.w > 0.f ? o.w : expm1f(o.w);
        }
        __half2* op = reinterpret_cast<__half2*>(xout + (size_t)v * 128 + dim4);
        op[0] = __float22half2_rn(make_float2(o.x, o.y));
        op[1] = __float22half2_rn(make_float2(o.z, o.w));
    }
}

// ---------------- layer 3: GEMM [N,128]x[128,6] -> padded h3p[N][8] ----------------

__global__ void gemm3_kernel(const __half* __restrict__ x, const float* __restrict__ W,
                             const float* __restrict__ as3, const float* __restrict__ ad3,
                             float* __restrict__ h3p, float* __restrict__ als3,
                             float* __restrict__ ald3, int N) {
    int n = blockIdx.x * blockDim.x + threadIdx.x;
    if (n >= N) return;
    float acc[6] = {0.f, 0.f, 0.f, 0.f, 0.f, 0.f};
    const __half* xp = x + (size_t)n * 128;
#pragma unroll 2
    for (int k8 = 0; k8 < 16; ++k8) {
        union { uint4 u; __half hh[8]; } rv;
        rv.u = *reinterpret_cast<const uint4*>(xp + k8 * 8);
        const float* w0 = W + (size_t)(k8 * 8) * 6;
#pragma unroll
        for (int kk = 0; kk < 8; ++kk) {
            float xv = (float)rv.hh[kk];
#pragma unroll
            for (int q = 0; q < 6; ++q)
                acc[q] += xv * w0[kk * 6 + q];
        }
    }
    float s = 0.f, d = 0.f;
#pragma unroll
    for (int q = 0; q < 6; ++q) {
        s += acc[q] * as3[q];
        d += acc[q] * ad3[q];
    }
    float4* hp = reinterpret_cast<float4*>(h3p + (size_t)n * 8);
    hp[0] = make_float4(acc[0], acc[1], acc[2], acc[3]);
    hp[1] = make_float4(acc[4], acc[5], 0.f, 0.f);
    als3[n] = s;
    ald3[n] = d;
}

// ---- final aggregation: 32 lanes/node = 4 edge-slots x 8 dims ----

__global__ __launch_bounds__(256) void agg3_kernel(const float* __restrict__ h3p,
                                                   const float* __restrict__ als3,
                                                   const float* __restrict__ ald3,
                                                   const int* __restrict__ row_start,
                                                   const int* __restrict__ csr_src,
                                                   const float* __restrict__ b3,
                                                   float* __restrict__ out, int N) {
    int v = (int)((blockIdx.x * blockDim.x + threadIdx.x) >> 5);
    int lane = threadIdx.x & 31;
    if (v >= N) return;
    int base = row_start[v], end = row_start[v + 1];
    int slot = lane >> 3;
    int dim  = lane & 7;

    float aldv = ald3[v];
    float em = lrelu(als3[v] + aldv);
    float acc = 0.f, ssum = 0.f;
    const char* hB = (const char*)h3p;
    const char* aB = (const char*)als3;
    unsigned dby = (unsigned)dim * 4;

    for (int j = base + slot; j < end; j += 4) {
        unsigned s = (unsigned)csr_src[j];
        float a = *(const float*)(aB + (s << 2));
        float hv = *(const float*)(hB + (s << 5) + dby);
        float e = __expf(lrelu(a + aldv) - em);
        ssum += e;
        acc += e * hv;
    }
    acc  += __shfl_xor(acc, 8);
    acc  += __shfl_xor(acc, 16);
    ssum += __shfl_xor(ssum, 8);
    ssum += __shfl_xor(ssum, 16);

    if (slot == 0 && dim < 6) {
        float inv = 1.f / (ssum + 1e-16f);
        out[(size_t)v * 6 + dim] = acc * inv + b3[dim];
    }
}

// ---------------- launch ----------------

extern "C" void kernel_launch(void* const* d_in, const int* in_sizes, int n_in,
                              void* d_out, int out_size, void* d_ws, size_t ws_size,
                              hipStream_t stream) {
    const float* x    = (const float*)d_in[0];
    const int*   ei   = (const int*)d_in[1];
    const float* W0   = (const float*)d_in[3];
    const float* as0  = (const float*)d_in[4];
    const float* ad0  = (const float*)d_in[5];
    const float* b0   = (const float*)d_in[6];
    const float* W1   = (const float*)d_in[7];
    const float* as1  = (const float*)d_in[8];
    const float* ad1  = (const float*)d_in[9];
    const float* b1   = (const float*)d_in[10];
    const float* W2   = (const float*)d_in[11];
    const float* as2  = (const float*)d_in[12];
    const float* ad2  = (const float*)d_in[13];
    const float* b2   = (const float*)d_in[14];
    const float* W3   = (const float*)d_in[15];
    const float* as3  = (const float*)d_in[16];
    const float* ad3  = (const float*)d_in[17];
    const float* b3   = (const float*)d_in[18];
    float* out = (float*)d_out;

    int N = in_sizes[0] / IN_CH;
    int E = in_sizes[1] / 2;
    int EN = E + N;
    int NB = (N + 255) >> 8;
    int epb = (EN + PBLK - 1) / PBLK;

    char* p = (char*)d_ws;
    auto alloc = [&](size_t bytes) {
        char* q = p;
        p += (bytes + 255) & ~(size_t)255;
        return q;
    };
    __half* hbuf = (__half*)alloc((size_t)N * 128 * 2);
    __half* xA   = (__half*)alloc((size_t)N * 128 * 2);
    __half* xB   = (__half*)alloc((size_t)N * 128 * 2);
    __half* WT0  = (__half*)alloc((size_t)128 * 64 * 2);
    __half* WT1  = (__half*)alloc((size_t)128 * 128 * 2);
    __half* WT2  = (__half*)alloc((size_t)128 * 128 * 2);
    float* als  = (float*)alloc((size_t)N * 4 * 4);
    float* ald  = (float*)alloc((size_t)N * 4 * 4);
    float* h3p  = (float*)alloc((size_t)N * 8 * 4);
    float* als3 = (float*)alloc((size_t)N * 4);
    float* ald3 = (float*)alloc((size_t)N * 4);
    int* row_start = (int*)alloc((size_t)(N + 1) * 4);
    int* csr_src   = (int*)alloc((size_t)EN * 4);
    int2* ebuf     = (int2*)alloc((size_t)EN * 8);
    int* counts    = (int*)alloc((size_t)NB * PBLK * 4);
    int* btot      = (int*)alloc((size_t)NB * 4);
    int* bstart    = (int*)alloc((size_t)(NB + 1) * 4);
    (void)ws_size; (void)n_in; (void)out_size;

    // ---- CSR build (no global atomics) ----
    part_count<<<PBLK, 256, 0, stream>>>(ei, E, EN, NB, epb, counts);
    bucket_tot<<<NB, 256, 0, stream>>>(counts, btot);
    bucket_scan<<<1, 256, 0, stream>>>(btot, NB, EN, bstart);
    bucket_base<<<NB, 256, 0, stream>>>(counts, bstart);
    part_scatter<<<PBLK, 256, 0, stream>>>(ei, E, EN, NB, epb, counts, ebuf);
    bucket_csr<<<NB, 256, 0, stream>>>(ebuf, bstart, NB, N, EN, row_start, csr_src);

    // ---- weight conversion (single launch) ----
    wtrans_all<<<(8192 + 32768 + 255) / 256, 256, 0, stream>>>(W0, W1, W2, WT0, WT1, WT2);

    int gemm_grid = (N + 63) / 64;
    int agg_grid  = (N + 3) / 4;
    int n_grid    = (N + 255) / 256;
    int agg3_grid = (N + 7) / 8;

    // ---- layer 0 (A read fp32 in-kernel) ----
    gemm_mfma<<<gemm_grid, 256, 0, stream>>>(nullptr, x, WT0, as0, ad0, hbuf, als, ald, N, 64);
    agg_kernel<<<agg_grid, 256, 0, stream>>>(hbuf, als, ald, row_start, csr_src, b0, xA, N, 1);

    // ---- layer 1 ----
    gemm_mfma<<<gemm_grid, 256, 0, stream>>>(xA, nullptr, WT1, as1, ad1, hbuf, als, ald, N, 128);
    agg_kernel<<<agg_grid, 256, 0, stream>>>(hbuf, als, ald, row_start, csr_src, b1, xB, N, 1);

    // ---- layer 2 ----
    gemm_mfma<<<gemm_grid, 256, 0, stream>>>(xB, nullptr, WT2, as2, ad2, hbuf, als, ald, N, 128);
    agg_kernel<<<agg_grid, 256, 0, stream>>>(hbuf, als, ald, row_start, csr_src, b2, xA, N, 1);

    // ---- layer 3 ----
    gemm3_kernel<<<n_grid, 256, 0, stream>>>(xA, W3, as3, ad3, h3p, als3, ald3, N);
    agg3_kernel<<<agg3_grid, 256, 0, stream>>>(h3p, als3, ald3, row_start, csr_src, b3, out, N);
}

// Round 15
// 421.336 us; speedup vs baseline: 1.0791x; 1.0521x over previous
//
#include <hip/hip_runtime.h>
#include <hip/hip_bf16.h>
#include <hip/hip_fp16.h>

#define IN_CH 64
#define HID 32
#define HEADS 4
#define OUT_CH 6
#define NEG_SLOPE 0.2f

typedef __attribute__((ext_vector_type(8))) _Float16 half8;
typedef __attribute__((ext_vector_type(4))) float f32x4;

#define PBLK 256
#define CAP 6144

// ------- MFMA GEMM tile body (shared by prologue layer-0 and layers 1/2) -------
// Per wave: 16 rows x 128 cols. f32mode (K=64): A fp32 + B from fp32 W (in-reg
// convert, 16-lane coalesced column reads). Else (K=128): A fp16, B from WT fp16.

__device__ __forceinline__ void gemm_tile(const __half* __restrict__ A,
                                          const float* __restrict__ Af,
                                          const __half* __restrict__ WT,
                                          const float* __restrict__ Wf,
                                          const float* __restrict__ avs,
                                          const float* __restrict__ avd,
                                          __half* __restrict__ C,
                                          float* __restrict__ als,
                                          float* __restrict__ ald,
                                          int N, int K, int blk, int tid) {
    int wv = tid >> 6, lane = tid & 63;
    int row0 = blk * 64 + wv * 16;
    int lrow = lane & 15;
    int lk = (lane >> 4) * 8;
    int garow = row0 + lrow;

    half8 afrag[4];
#pragma unroll
    for (int ks = 0; ks < 4; ++ks) {
        half8 z = {(_Float16)0, (_Float16)0, (_Float16)0, (_Float16)0,
                   (_Float16)0, (_Float16)0, (_Float16)0, (_Float16)0};
        afrag[ks] = z;
    }
    if (garow < N) {
        if (K == 128) {
            const __half* ap = A + (size_t)garow * 128 + lk;
#pragma unroll
            for (int ks = 0; ks < 4; ++ks)
                afrag[ks] = *reinterpret_cast<const half8*>(ap + ks * 32);
        } else {
            const float* ap = Af + (size_t)garow * 64 + lk;
#pragma unroll
            for (int ks = 0; ks < 2; ++ks) {
                float4 f0 = *reinterpret_cast<const float4*>(ap + ks * 32);
                float4 f1 = *reinterpret_cast<const float4*>(ap + ks * 32 + 4);
                half8 fr = {(_Float16)f0.x, (_Float16)f0.y, (_Float16)f0.z, (_Float16)f0.w,
                            (_Float16)f1.x, (_Float16)f1.y, (_Float16)f1.z, (_Float16)f1.w};
                afrag[ks] = fr;
            }
        }
    }

    f32x4 acc[8];
#pragma unroll
    for (int t = 0; t < 8; ++t) acc[t] = (f32x4){0.f, 0.f, 0.f, 0.f};

#pragma unroll
    for (int t = 0; t < 8; ++t) {
        int c = t * 16 + lrow;
        if (K == 128) {
            const __half* wb = WT + (size_t)c * 128 + lk;
#pragma unroll
            for (int ks = 0; ks < 4; ++ks) {
                half8 bfrag = *reinterpret_cast<const half8*>(wb + ks * 32);
                acc[t] = __builtin_amdgcn_mfma_f32_16x16x32_f16(afrag[ks], bfrag, acc[t], 0, 0, 0);
            }
        } else {
            const float* wcol = Wf + c;
#pragma unroll
            for (int ks = 0; ks < 2; ++ks) {
                half8 bfrag;
#pragma unroll
                for (int jj = 0; jj < 8; ++jj)
                    bfrag[jj] = (_Float16)wcol[(size_t)(ks * 32 + lk + jj) * 128];
                acc[t] = __builtin_amdgcn_mfma_f32_16x16x32_f16(afrag[ks], bfrag, acc[t], 0, 0, 0);
            }
        }
    }

    int rbase = (lane >> 4) * 4;
#pragma unroll
    for (int t = 0; t < 8; ++t) {
#pragma unroll
        for (int j = 0; j < 4; ++j) {
            int gr = row0 + rbase + j;
            if (gr < N) C[(size_t)gr * 128 + t * 16 + lrow] = __float2half(acc[t][j]);
        }
    }
    float ps[4][4], pd[4][4];
#pragma unroll
    for (int h = 0; h < 4; ++h)
#pragma unroll
        for (int j = 0; j < 4; ++j) { ps[h][j] = 0.f; pd[h][j] = 0.f; }
#pragma unroll
    for (int t = 0; t < 8; ++t) {
        int ht = t >> 1;
        float as_c = avs[t * 16 + lrow];
        float ad_c = avd[t * 16 + lrow];
#pragma unroll
        for (int j = 0; j < 4; ++j) {
            ps[ht][j] += acc[t][j] * as_c;
            pd[ht][j] += acc[t][j] * ad_c;
        }
    }
#pragma unroll
    for (int h = 0; h < 4; ++h) {
#pragma unroll
        for (int j = 0; j < 4; ++j) {
            float s = ps[h][j], d = pd[h][j];
            s += __shfl_xor(s, 1); d += __shfl_xor(d, 1);
            s += __shfl_xor(s, 2); d += __shfl_xor(d, 2);
            s += __shfl_xor(s, 4); d += __shfl_xor(d, 4);
            s += __shfl_xor(s, 8); d += __shfl_xor(d, 8);
            if (lrow == 0) {
                int gr = row0 + rbase + j;
                if (gr < N) {
                    als[(size_t)gr * 4 + h] = s;
                    ald[(size_t)gr * 4 + h] = d;
                }
            }
        }
    }
}

// ============== Prologue: part_count ∥ wtrans(W1,W2) ∥ gemm layer-0 ==============
// All three independent; blockIdx range split. gemm0 reads W0 fp32 directly
// (no WT0 -> no intra-kernel write/read race).

__global__ __launch_bounds__(256) void prologue_kernel(
        const int* __restrict__ ei, int E, int EN, int NB, int epb,
        int* __restrict__ counts,
        const float* __restrict__ W1, const float* __restrict__ W2,
        __half* __restrict__ WT1, __half* __restrict__ WT2,
        const float* __restrict__ x, const float* __restrict__ W0,
        const float* __restrict__ avs, const float* __restrict__ avd,
        __half* __restrict__ C, float* __restrict__ als, float* __restrict__ ald,
        int N) {
    __shared__ int cnt[512];
    int b = blockIdx.x, t = threadIdx.x;
    if (b < PBLK) {
        // ---- part_count ----
        for (int i = t; i < NB; i += 256) cnt[i] = 0;
        __syncthreads();
        int e0 = b * epb;
        int e1 = min(e0 + epb, EN);
        for (int e = e0 + t; e < e1; e += 256) {
            int d = (e < E) ? ei[E + e] : (e - E);
            atomicAdd(&cnt[d >> 8], 1);
        }
        __syncthreads();
        for (int i = t; i < NB; i += 256) counts[(size_t)i * PBLK + b] = cnt[i];
    } else if (b < PBLK + 128) {
        // ---- wtrans W1, W2 (32768 elems) ----
        int i = (b - PBLK) * 256 + t;
        if (i < 16384) {
            int c = i >> 7, k = i & 127;
            WT1[i] = __float2half(W1[(size_t)k * 128 + c]);
        } else {
            int i2 = i - 16384;
            int c = i2 >> 7, k = i2 & 127;
            WT2[i2] = __float2half(W2[(size_t)k * 128 + c]);
        }
    } else {
        // ---- gemm layer 0 (K=64, fp32 A and W) ----
        gemm_tile(nullptr, x, nullptr, W0, avs, avd, C, als, ald, N, 64, b - PBLK - 128, t);
    }
}

// ---------------- standalone MFMA GEMM (layers 1,2) ----------------

__global__ __launch_bounds__(256) void gemm_mfma(const __half* __restrict__ A,
                                                 const __half* __restrict__ WT,
                                                 const float* __restrict__ avs,
                                                 const float* __restrict__ avd,
                                                 __half* __restrict__ C,
                                                 float* __restrict__ als,
                                                 float* __restrict__ ald,
                                                 int N) {
    gemm_tile(A, nullptr, WT, nullptr, avs, avd, C, als, ald, N, 128,
              blockIdx.x, threadIdx.x);
}

// ============== CSR build tail (unchanged except packed ebuf) ==============

__global__ __launch_bounds__(256) void bucket_tot(const int* __restrict__ counts,
                                                  int* __restrict__ btot) {
    __shared__ int red[256];
    int k = blockIdx.x, t = threadIdx.x;
    red[t] = counts[(size_t)k * PBLK + t];
    __syncthreads();
    for (int off = 128; off; off >>= 1) {
        if (t < off) red[t] += red[t + off];
        __syncthreads();
    }
    if (t == 0) btot[k] = red[0];
}

__global__ __launch_bounds__(256) void bucket_scan(const int* __restrict__ btot, int NB, int EN,
                                                   int* __restrict__ bstart) {
    __shared__ int tmp[256];
    int t = threadIdx.x;
    int chunk = (NB + 255) >> 8;
    int s0 = t * chunk, s1 = min(s0 + chunk, NB);
    int sum = 0;
    for (int i = s0; i < s1; ++i) sum += btot[i];
    tmp[t] = sum;
    __syncthreads();
    for (int off = 1; off < 256; off <<= 1) {
        int v = (t >= off) ? tmp[t - off] : 0;
        __syncthreads();
        tmp[t] += v;
        __syncthreads();
    }
    int run = (t == 0) ? 0 : tmp[t - 1];
    for (int i = s0; i < s1; ++i) {
        int c = btot[i];
        bstart[i] = run;
        run += c;
    }
    if (t == 255) bstart[NB] = EN;
}

__global__ __launch_bounds__(256) void bucket_base(int* __restrict__ counts,
                                                   const int* __restrict__ bstart) {
    __shared__ int sc[256];
    int k = blockIdx.x, t = threadIdx.x;
    int v = counts[(size_t)k * PBLK + t];
    sc[t] = v;
    __syncthreads();
    for (int off = 1; off < 256; off <<= 1) {
        int u = (t >= off) ? sc[t - off] : 0;
        __syncthreads();
        sc[t] += u;
        __syncthreads();
    }
    counts[(size_t)k * PBLK + t] = bstart[k] + sc[t] - v;
}

__global__ __launch_bounds__(256) void part_scatter(const int* __restrict__ ei, int E, int EN,
                                                    int NB, int epb,
                                                    const int* __restrict__ base,
                                                    int* __restrict__ ebuf) {
    __shared__ int cur[512];
    int b = blockIdx.x, t = threadIdx.x;
    for (int i = t; i < NB; i += 256) cur[i] = base[(size_t)i * PBLK + b];
    __syncthreads();
    int e0 = b * epb;
    int e1 = min(e0 + epb, EN);
    for (int e = e0 + t; e < e1; e += 256) {
        int s, d;
        if (e < E) { s = ei[e]; d = ei[E + e]; }
        else       { s = e - E; d = s; }
        int slot = atomicAdd(&cur[d >> 8], 1);
        ebuf[slot] = (s << 8) | (d & 255);    // pack: src<<8 | dlocal
    }
}

__global__ __launch_bounds__(256) void bucket_csr(const int* __restrict__ ebuf,
                                                  const int* __restrict__ bstart,
                                                  int NB, int N, int EN,
                                                  int* __restrict__ row_start,
                                                  int* __restrict__ csr_src) {
    __shared__ int cnt[256];
    __shared__ int sc[256];
    __shared__ int stage[CAP];
    int k = blockIdx.x, t = threadIdx.x;
    int s0 = bstart[k], s1 = bstart[k + 1];
    int len = s1 - s0;
    cnt[t] = 0;
    __syncthreads();
    for (int i = t; i < len; i += 256) atomicAdd(&cnt[ebuf[s0 + i] & 255], 1);
    __syncthreads();
    int v = cnt[t];
    sc[t] = v;
    __syncthreads();
    for (int off = 1; off < 256; off <<= 1) {
        int u = (t >= off) ? sc[t - off] : 0;
        __syncthreads();
        sc[t] += u;
        __syncthreads();
    }
    int excl = sc[t] - v;
    int g = (k << 8) + t;
    if (g < N) row_start[g] = s0 + excl;
    if (k == NB - 1 && t == 0) row_start[N] = EN;
    bool fits = (len <= CAP);
    cnt[t] = fits ? excl : s0 + excl;
    __syncthreads();
    if (fits) {
        for (int i = t; i < len; i += 256) {
            int e = ebuf[s0 + i];
            int slot = atomicAdd(&cnt[e & 255], 1);
            stage[slot] = (int)((unsigned)e >> 8);
        }
        __syncthreads();
        for (int i = t; i < len; i += 256) csr_src[s0 + i] = stage[i];
    } else {
        for (int i = t; i < len; i += 256) {
            int e = ebuf[s0 + i];
            int slot = atomicAdd(&cnt[e & 255], 1);
            csr_src[slot] = (int)((unsigned)e >> 8);
        }
    }
}

// ------- wave-per-node aggregation (layers 0-2), fp16 h — flat form -------

__device__ __forceinline__ float lrelu(float x) { return x > 0.f ? x : NEG_SLOPE * x; }

__global__ __launch_bounds__(256) void agg_kernel(const __half* __restrict__ h,
                                                  const float* __restrict__ als4,
                                                  const float* __restrict__ ald4,
                                                  const int* __restrict__ row_start,
                                                  const int* __restrict__ csr_src,
                                                  const float* __restrict__ bias,
                                                  __half* __restrict__ xout,
                                                  int N, int applyElu) {
    int v = (int)((blockIdx.x * blockDim.x + threadIdx.x) >> 6);
    int lane = threadIdx.x & 63;
    if (v >= N) return;
    int base = row_start[v], end = row_start[v + 1];

    int half_ = lane >> 5;
    int dim4 = (lane & 31) * 4;
    int hd2  = (lane & 31) >> 3;

    float aldh = ald4[(size_t)v * 4 + hd2];
    float alsh = als4[(size_t)v * 4 + hd2];
    float em = lrelu(alsh + aldh);

    const char* hB = (const char*)h;
    const char* aB = (const char*)als4;
    unsigned dby = (unsigned)dim4 * 2;
    unsigned aby = (unsigned)hd2 * 4;

    float4 acc  = make_float4(0.f, 0.f, 0.f, 0.f);
    float4 acc2 = make_float4(0.f, 0.f, 0.f, 0.f);
    float ssum = 0.f, ssum2 = 0.f;

    union H4 { uint2 u; __half hh[4]; };

    int j = base + half_;
    for (; j + 6 < end; j += 8) {
        unsigned s0 = (unsigned)csr_src[j + 0];
        unsigned s1 = (unsigned)csr_src[j + 2];
        unsigned s2 = (unsigned)csr_src[j + 4];
        unsigned s3 = (unsigned)csr_src[j + 6];
        float a0 = *(const float*)(aB + (s0 << 4) + aby);
        float a1 = *(const float*)(aB + (s1 << 4) + aby);
        float a2 = *(const float*)(aB + (s2 << 4) + aby);
        float a3 = *(const float*)(aB + (s3 << 4) + aby);
        H4 r0, r1, r2, r3;
        r0.u = *(const uint2*)(hB + (s0 << 8) + dby);
        r1.u = *(const uint2*)(hB + (s1 << 8) + dby);
        r2.u = *(const uint2*)(hB + (s2 << 8) + dby);
        r3.u = *(const uint2*)(hB + (s3 << 8) + dby);
        float e0 = __expf(lrelu(a0 + aldh) - em);
        float e1 = __expf(lrelu(a1 + aldh) - em);
        float e2 = __expf(lrelu(a2 + aldh) - em);
        float e3 = __expf(lrelu(a3 + aldh) - em);
        ssum  += e0 + e2;
        ssum2 += e1 + e3;
        acc.x  += e0 * (float)r0.hh[0]; acc.y  += e0 * (float)r0.hh[1];
        acc.z  += e0 * (float)r0.hh[2]; acc.w  += e0 * (float)r0.hh[3];
        acc2.x += e1 * (float)r1.hh[0]; acc2.y += e1 * (float)r1.hh[1];
        acc2.z += e1 * (float)r1.hh[2]; acc2.w += e1 * (float)r1.hh[3];
        acc.x  += e2 * (float)r2.hh[0]; acc.y  += e2 * (float)r2.hh[1];
        acc.z  += e2 * (float)r2.hh[2]; acc.w  += e2 * (float)r2.hh[3];
        acc2.x += e3 * (float)r3.hh[0]; acc2.y += e3 * (float)r3.hh[1];
        acc2.z += e3 * (float)r3.hh[2]; acc2.w += e3 * (float)r3.hh[3];
    }
    for (; j < end; j += 2) {
        unsigned s0 = (unsigned)csr_src[j];
        float a0 = *(const float*)(aB + (s0 << 4) + aby);
        H4 r0;
        r0.u = *(const uint2*)(hB + (s0 << 8) + dby);
        float e0 = __expf(lrelu(a0 + aldh) - em);
        ssum += e0;
        acc.x += e0 * (float)r0.hh[0]; acc.y += e0 * (float)r0.hh[1];
        acc.z += e0 * (float)r0.hh[2]; acc.w += e0 * (float)r0.hh[3];
    }
    acc.x += acc2.x; acc.y += acc2.y; acc.z += acc2.z; acc.w += acc2.w;
    ssum += ssum2;
    acc.x += __shfl_xor(acc.x, 32);
    acc.y += __shfl_xor(acc.y, 32);
    acc.z += __shfl_xor(acc.z, 32);
    acc.w += __shfl_xor(acc.w, 32);
    ssum  += __shfl_xor(ssum, 32);

    if (lane < 32) {
        float inv = 1.0f / (ssum + 1e-16f);
        float4 bv = *reinterpret_cast<const float4*>(bias + dim4);
        float4 o;
        o.x = acc.x * inv + bv.x;
        o.y = acc.y * inv + bv.y;
        o.z = acc.z * inv + bv.z;
        o.w = acc.w * inv + bv.w;
        if (applyElu) {
            o.x = o.x > 0.f ? o.x : expm1f(o.x);
            o.y = o.y > 0.f ? o.y : expm1f(o.y);
            o.z = o.z > 0.f ? o.z : expm1f(o.z);
            o.w = o.w > 0.f ? o.w : expm1f(o.w);
        }
        __half2* op = reinterpret_cast<__half2*>(xout + (size_t)v * 128 + dim4);
        op[0] = __float22half2_rn(make_float2(o.x, o.y));
        op[1] = __float22half2_rn(make_float2(o.z, o.w));
    }
}

// ---------------- layer 3: GEMM [N,128]x[128,6] -> padded h3p[N][8] ----------------

__global__ void gemm3_kernel(const __half* __restrict__ x, const float* __restrict__ W,
                             const float* __restrict__ as3, const float* __restrict__ ad3,
                             float* __restrict__ h3p, float* __restrict__ als3,
                             float* __restrict__ ald3, int N) {
    int n = blockIdx.x * blockDim.x + threadIdx.x;
    if (n >= N) return;
    float acc[6] = {0.f, 0.f, 0.f, 0.f, 0.f, 0.f};
    const __half* xp = x + (size_t)n * 128;
#pragma unroll 2
    for (int k8 = 0; k8 < 16; ++k8) {
        union { uint4 u; __half hh[8]; } rv;
        rv.u = *reinterpret_cast<const uint4*>(xp + k8 * 8);
        const float* w0 = W + (size_t)(k8 * 8) * 6;
#pragma unroll
        for (int kk = 0; kk < 8; ++kk) {
            float xv = (float)rv.hh[kk];
#pragma unroll
            for (int q = 0; q < 6; ++q)
                acc[q] += xv * w0[kk * 6 + q];
        }
    }
    float s = 0.f, d = 0.f;
#pragma unroll
    for (int q = 0; q < 6; ++q) {
        s += acc[q] * as3[q];
        d += acc[q] * ad3[q];
    }
    float4* hp = reinterpret_cast<float4*>(h3p + (size_t)n * 8);
    hp[0] = make_float4(acc[0], acc[1], acc[2], acc[3]);
    hp[1] = make_float4(acc[4], acc[5], 0.f, 0.f);
    als3[n] = s;
    ald3[n] = d;
}

// ---- final aggregation: 32 lanes/node = 4 edge-slots x 8 dims ----

__global__ __launch_bounds__(256) void agg3_kernel(const float* __restrict__ h3p,
                                                   const float* __restrict__ als3,
                                                   const float* __restrict__ ald3,
                                                   const int* __restrict__ row_start,
                                                   const int* __restrict__ csr_src,
                                                   const float* __restrict__ b3,
                                                   float* __restrict__ out, int N) {
    int v = (int)((blockIdx.x * blockDim.x + threadIdx.x) >> 5);
    int lane = threadIdx.x & 31;
    if (v >= N) return;
    int base = row_start[v], end = row_start[v + 1];
    int slot = lane >> 3;
    int dim  = lane & 7;

    float aldv = ald3[v];
    float em = lrelu(als3[v] + aldv);
    float acc = 0.f, ssum = 0.f;
    const char* hB = (const char*)h3p;
    const char* aB = (const char*)als3;
    unsigned dby = (unsigned)dim * 4;

    for (int j = base + slot; j < end; j += 4) {
        unsigned s = (unsigned)csr_src[j];
        float a = *(const float*)(aB + (s << 2));
        float hv = *(const float*)(hB + (s << 5) + dby);
        float e = __expf(lrelu(a + aldv) - em);
        ssum += e;
        acc += e * hv;
    }
    acc  += __shfl_xor(acc, 8);
    acc  += __shfl_xor(acc, 16);
    ssum += __shfl_xor(ssum, 8);
    ssum += __shfl_xor(ssum, 16);

    if (slot == 0 && dim < 6) {
        float inv = 1.f / (ssum + 1e-16f);
        out[(size_t)v * 6 + dim] = acc * inv + b3[dim];
    }
}

// ---------------- launch ----------------

extern "C" void kernel_launch(void* const* d_in, const int* in_sizes, int n_in,
                              void* d_out, int out_size, void* d_ws, size_t ws_size,
                              hipStream_t stream) {
    const float* x    = (const float*)d_in[0];
    const int*   ei   = (const int*)d_in[1];
    const float* W0   = (const float*)d_in[3];
    const float* as0  = (const float*)d_in[4];
    const float* ad0  = (const float*)d_in[5];
    const float* b0   = (const float*)d_in[6];
    const float* W1   = (const float*)d_in[7];
    const float* as1  = (const float*)d_in[8];
    const float* ad1  = (const float*)d_in[9];
    const float* b1   = (const float*)d_in[10];
    const float* W2   = (const float*)d_in[11];
    const float* as2  = (const float*)d_in[12];
    const float* ad2  = (const float*)d_in[13];
    const float* b2   = (const float*)d_in[14];
    const float* W3   = (const float*)d_in[15];
    const float* as3  = (const float*)d_in[16];
    const float* ad3  = (const float*)d_in[17];
    const float* b3   = (const float*)d_in[18];
    float* out = (float*)d_out;

    int N = in_sizes[0] / IN_CH;
    int E = in_sizes[1] / 2;
    int EN = E + N;
    int NB = (N + 255) >> 8;
    int epb = (EN + PBLK - 1) / PBLK;

    char* p = (char*)d_ws;
    auto alloc = [&](size_t bytes) {
        char* q = p;
        p += (bytes + 255) & ~(size_t)255;
        return q;
    };
    __half* hbuf = (__half*)alloc((size_t)N * 128 * 2);
    __half* xA   = (__half*)alloc((size_t)N * 128 * 2);
    __half* xB   = (__half*)alloc((size_t)N * 128 * 2);
    __half* WT1  = (__half*)alloc((size_t)128 * 128 * 2);
    __half* WT2  = (__half*)alloc((size_t)128 * 128 * 2);
    float* als  = (float*)alloc((size_t)N * 4 * 4);
    float* ald  = (float*)alloc((size_t)N * 4 * 4);
    float* h3p  = (float*)alloc((size_t)N * 8 * 4);
    float* als3 = (float*)alloc((size_t)N * 4);
    float* ald3 = (float*)alloc((size_t)N * 4);
    int* row_start = (int*)alloc((size_t)(N + 1) * 4);
    int* csr_src   = (int*)alloc((size_t)EN * 4);
    int* ebuf      = (int*)alloc((size_t)EN * 4);
    int* counts    = (int*)alloc((size_t)NB * PBLK * 4);
    int* btot      = (int*)alloc((size_t)NB * 4);
    int* bstart    = (int*)alloc((size_t)(NB + 1) * 4);
    (void)ws_size; (void)n_in; (void)out_size;

    int gemm_grid = (N + 63) / 64;
    int agg_grid  = (N + 3) / 4;
    int n_grid    = (N + 255) / 256;
    int agg3_grid = (N + 7) / 8;

    // ---- prologue: part_count ∥ wtrans(W1,W2) ∥ gemm layer-0 ----
    prologue_kernel<<<PBLK + 128 + gemm_grid, 256, 0, stream>>>(
        ei, E, EN, NB, epb, counts, W1, W2, WT1, WT2,
        x, W0, as0, ad0, hbuf, als, ald, N);

    // ---- CSR build tail ----
    bucket_tot<<<NB, 256, 0, stream>>>(counts, btot);
    bucket_scan<<<1, 256, 0, stream>>>(btot, NB, EN, bstart);
    bucket_base<<<NB, 256, 0, stream>>>(counts, bstart);
    part_scatter<<<PBLK, 256, 0, stream>>>(ei, E, EN, NB, epb, counts, ebuf);
    bucket_csr<<<NB, 256, 0, stream>>>(ebuf, bstart, NB, N, EN, row_start, csr_src);

    // ---- layer 0 aggregation ----
    agg_kernel<<<agg_grid, 256, 0, stream>>>(hbuf, als, ald, row_start, csr_src, b0, xA, N, 1);

    // ---- layer 1 ----
    gemm_mfma<<<gemm_grid, 256, 0, stream>>>(xA, WT1, as1, ad1, hbuf, als, ald, N);
    agg_kernel<<<agg_grid, 256, 0, stream>>>(hbuf, als, ald, row_start, csr_src, b1, xB, N, 1);

    // ---- layer 2 ----
    gemm_mfma<<<gemm_grid, 256, 0, stream>>>(xB, WT2, as2, ad2, hbuf, als, ald, N);
    agg_kernel<<<agg_grid, 256, 0, stream>>>(hbuf, als, ald, row_start, csr_src, b2, xA, N, 1);

    // ---- layer 3 ----
    gemm3_kernel<<<n_grid, 256, 0, stream>>>(xA, W3, as3, ad3, h3p, als3, ald3, N);
    agg3_kernel<<<agg3_grid, 256, 0, stream>>>(h3p, als3, ald3, row_start, csr_src, b3, out, N);
}